// Round 1
// baseline (2747.756 us; speedup 1.0000x reference)
//
#include <hip/hip_runtime.h>
#include <cstddef>

// Problem constants (reference: B=1, T=2048, E=1024, H=16, D=64)
#define TT 2048
#define EE 1024
#define HH 16
#define DDIM 64

// ---------------------------------------------------------------------------
// Tiled fp32 GEMM, 64x64 tile, BK=16, 256 threads, 4x4 microtile.
// C = A @ (BT ? B^T : B).  A: (M,K) row-major.
//   BT=true : B is (N,K) row-major (we compute A @ B^T)
//   BT=false: B is (K,N) row-major
// OUTMODE 0: C[m*N + n]   (row-major M x N)
// OUTMODE 1: C[((n>>6)*M + m)*64 + (n&63)]   -> (H, M, 64) head layout
// Requires M,N % 64 == 0, K % 16 == 0.
// ---------------------------------------------------------------------------
template<bool BT, int OUTMODE>
__global__ __launch_bounds__(256) void gemm64(
    const float* __restrict__ A, const float* __restrict__ B,
    float* __restrict__ C, int M, int N, int K)
{
  __shared__ float As[16][68];
  __shared__ float Bs[16][68];
  const int tid = threadIdx.x;
  const int m0 = blockIdx.y * 64, n0 = blockIdx.x * 64;
  const int tr = tid >> 4, tc = tid & 15;
  float acc[4][4] = {};
  for (int k0 = 0; k0 < K; k0 += 16) {
#pragma unroll
    for (int i = 0; i < 4; ++i) {
      int m = (tid >> 4) + i * 16;
      int k = tid & 15;
      As[k][m] = A[(size_t)(m0 + m) * K + (k0 + k)];
    }
    if (BT) {
#pragma unroll
      for (int i = 0; i < 4; ++i) {
        int n = (tid >> 4) + i * 16;
        int k = tid & 15;
        Bs[k][n] = B[(size_t)(n0 + n) * K + (k0 + k)];
      }
    } else {
#pragma unroll
      for (int i = 0; i < 4; ++i) {
        int k = (tid >> 6) + i * 4;
        int n = tid & 63;
        Bs[k][n] = B[(size_t)(k0 + k) * N + (n0 + n)];
      }
    }
    __syncthreads();
#pragma unroll
    for (int k = 0; k < 16; ++k) {
      float a[4], b[4];
#pragma unroll
      for (int i = 0; i < 4; ++i) a[i] = As[k][tr * 4 + i];
#pragma unroll
      for (int j = 0; j < 4; ++j) b[j] = Bs[k][tc * 4 + j];
#pragma unroll
      for (int i = 0; i < 4; ++i)
#pragma unroll
        for (int j = 0; j < 4; ++j)
          acc[i][j] += a[i] * b[j];
    }
    __syncthreads();
  }
#pragma unroll
  for (int i = 0; i < 4; ++i) {
    int m = m0 + tr * 4 + i;
#pragma unroll
    for (int j = 0; j < 4; ++j) {
      int n = n0 + tc * 4 + j;
      if (OUTMODE == 0) C[(size_t)m * N + n] = acc[i][j];
      else C[((size_t)(n >> 6) * M + m) * 64 + (n & 63)] = acc[i][j];
    }
  }
}

// ---------------------------------------------------------------------------
// Branch 1: causal flash attention, fp32. One block = (head, 64 q-rows).
// Q,K,V,O in (H,T,D=64) layout. scale folded into q registers.
// Thread (r = tid>>2, quad = tid&3): S phase computes 16 k's for row r;
// PV phase accumulates d-slice quad*16..+15 for row r.
// ---------------------------------------------------------------------------
__global__ __launch_bounds__(256) void flash_qkv(
    const float* __restrict__ Q, const float* __restrict__ K,
    const float* __restrict__ V, float* __restrict__ O, int T)
{
  const int h = blockIdx.x;
  const int q0 = blockIdx.y * 64;
  const int tid = threadIdx.x;
  const int r = tid >> 2;
  const int quad = tid & 3;
  const float scale = 0.125f; // 1/sqrt(64)
  const float* Qh = Q + (size_t)h * T * 64;
  const float* Kh = K + (size_t)h * T * 64;
  const float* Vh = V + (size_t)h * T * 64;

  __shared__ float Ks[64][65];
  __shared__ float Vs[64][65];
  __shared__ float Ps[64][65];

  float qreg[64];
  {
    const float* qrow = Qh + (size_t)(q0 + r) * 64;
#pragma unroll
    for (int d4 = 0; d4 < 16; ++d4) {
      float4 qq = ((const float4*)qrow)[d4];
      qreg[d4 * 4 + 0] = qq.x * scale;
      qreg[d4 * 4 + 1] = qq.y * scale;
      qreg[d4 * 4 + 2] = qq.z * scale;
      qreg[d4 * 4 + 3] = qq.w * scale;
    }
  }

  float acc[16] = {};
  float m = -1e30f, l = 0.f;
  const int ntiles = (q0 >> 6) + 1;

  for (int kt = 0; kt < ntiles; ++kt) {
    const int k0 = kt * 64;
    __syncthreads();
    // load K,V tile (coalesced, 16 floats per thread)
#pragma unroll
    for (int i = 0; i < 16; ++i) {
      int e = tid + i * 256;
      int row = e >> 6, col = e & 63;
      Ks[row][col] = Kh[(size_t)(k0 + row) * 64 + col];
      Vs[row][col] = Vh[(size_t)(k0 + row) * 64 + col];
    }
    __syncthreads();

    float sv[16];
#pragma unroll
    for (int j = 0; j < 16; ++j) {
      const int kj = quad * 16 + j;
      float sdot = 0.f;
#pragma unroll
      for (int d = 0; d < 64; ++d) sdot += qreg[d] * Ks[kj][d];
      if (k0 + kj > q0 + r) sdot = -1e30f; // causal mask
      sv[j] = sdot;
    }
    float tm = sv[0];
#pragma unroll
    for (int j = 1; j < 16; ++j) tm = fmaxf(tm, sv[j]);
    tm = fmaxf(tm, __shfl_xor(tm, 1));
    tm = fmaxf(tm, __shfl_xor(tm, 2));
    float mnew = fmaxf(m, tm);
    float alpha = __expf(m - mnew);
    float ps = 0.f;
#pragma unroll
    for (int j = 0; j < 16; ++j) {
      float p = __expf(sv[j] - mnew);
      ps += p;
      Ps[r][quad * 16 + j] = p;
    }
    ps += __shfl_xor(ps, 1);
    ps += __shfl_xor(ps, 2);
    l = l * alpha + ps;
    m = mnew;
#pragma unroll
    for (int dd = 0; dd < 16; ++dd) acc[dd] *= alpha;
    __syncthreads();
    for (int k = 0; k < 64; ++k) {
      float p = Ps[r][k];
#pragma unroll
      for (int dd = 0; dd < 16; ++dd)
        acc[dd] += p * Vs[k][quad * 16 + dd];
    }
  }
  float invl = 1.f / l;
  float* Oh = O + (size_t)h * T * 64;
#pragma unroll
  for (int dd = 0; dd < 16; ++dd)
    Oh[(size_t)(q0 + r) * 64 + quad * 16 + dd] = acc[dd] * invl;
}

// ---------------------------------------------------------------------------
// Branch 2 helpers
// ---------------------------------------------------------------------------
// r[h][t] = sum_e x[t][e] * wr[h][e][t]
__global__ __launch_bounds__(256) void rscore_kernel(
    const float* __restrict__ x, const float* __restrict__ wr,
    float* __restrict__ r, int T, int E)
{
  const int h = blockIdx.y;
  const int t = blockIdx.x * 256 + threadIdx.x;
  const float* wrh = wr + (size_t)h * E * T;
  float acc = 0.f;
  for (int e = 0; e < E; ++e)
    acc += x[(size_t)t * E + e] * wrh[(size_t)e * T + t];
  r[(size_t)h * T + t] = acc;
}

// w[h][t] = exp((r[h][t] - max_t r[h][t]) * 1/8)
__global__ __launch_bounds__(256) void rsoftmax_kernel(
    const float* __restrict__ r, float* __restrict__ w, int T)
{
  const int h = blockIdx.x;
  const float* rh = r + (size_t)h * T;
  float mx = -1e30f;
  for (int t = threadIdx.x; t < T; t += 256) mx = fmaxf(mx, rh[t]);
#pragma unroll
  for (int o = 32; o; o >>= 1) mx = fmaxf(mx, __shfl_xor(mx, o));
  __shared__ float red[4];
  if ((threadIdx.x & 63) == 0) red[threadIdx.x >> 6] = mx;
  __syncthreads();
  mx = fmaxf(fmaxf(red[0], red[1]), fmaxf(red[2], red[3]));
  float* wh = w + (size_t)h * T;
  for (int t = threadIdx.x; t < T; t += 256)
    wh[t] = __expf((rh[t] - mx) * 0.125f);
}

// prefix-softmax-weighted running average: out[h][q][d] = num/den over k<=q
__global__ __launch_bounds__(64) void rrp_scan_kernel(
    const float* __restrict__ w, const float* __restrict__ rv,
    float* __restrict__ out, int T)
{
  const int h = blockIdx.x;
  const int d = threadIdx.x; // 0..63
  const float* wh = w + (size_t)h * T;
  const float* rvh = rv + (size_t)h * T * 64;
  float* oh = out + (size_t)h * T * 64;
  float num = 0.f, den = 0.f;
  for (int k = 0; k < T; ++k) {
    float wk = wh[k];
    num += wk * rvh[(size_t)k * 64 + d];
    den += wk;
    oh[(size_t)k * 64 + d] = num / den;
  }
}

// ---------------------------------------------------------------------------
// Branch 3 helpers
// ---------------------------------------------------------------------------
// s[t] = dot(x[t], echo_back[t]) / sqrt(E)
__global__ __launch_bounds__(256) void sscore_kernel(
    const float* __restrict__ x, const float* __restrict__ eb,
    float* __restrict__ s, int E)
{
  const int t = blockIdx.x;
  const size_t base = (size_t)t * E;
  float acc = 0.f;
  for (int e = threadIdx.x; e < E; e += 256)
    acc += x[base + e] * eb[base + e];
#pragma unroll
  for (int o = 32; o; o >>= 1) acc += __shfl_xor(acc, o);
  __shared__ float red[4];
  if ((threadIdx.x & 63) == 0) red[threadIdx.x >> 6] = acc;
  __syncthreads();
  if (threadIdx.x == 0)
    s[t] = (red[0] + red[1] + red[2] + red[3]) * 0.03125f; // 1/sqrt(1024)
}

// W[q][k] = (k<=q) ? exp(s_q*s_k - max_{k<=q} s_q*s_k) : 0 ; den[q] = row sum
__global__ __launch_bounds__(256) void janus_w_kernel(
    const float* __restrict__ s, float* __restrict__ W,
    float* __restrict__ den, int T)
{
  const int q = blockIdx.x;
  const float sq = s[q];
  float mx = -1e30f;
  for (int k = threadIdx.x; k <= q; k += 256) mx = fmaxf(mx, sq * s[k]);
#pragma unroll
  for (int o = 32; o; o >>= 1) mx = fmaxf(mx, __shfl_xor(mx, o));
  __shared__ float red[4];
  if ((threadIdx.x & 63) == 0) red[threadIdx.x >> 6] = mx;
  __syncthreads();
  mx = fmaxf(fmaxf(red[0], red[1]), fmaxf(red[2], red[3]));
  float sum = 0.f;
  float* Wq = W + (size_t)q * T;
  for (int k = threadIdx.x; k < T; k += 256) {
    float wv = (k <= q) ? __expf(sq * s[k] - mx) : 0.f;
    Wq[k] = wv;
    sum += wv;
  }
#pragma unroll
  for (int o = 32; o; o >>= 1) sum += __shfl_xor(sum, o);
  __syncthreads(); // protect red[] reuse
  if ((threadIdx.x & 63) == 0) red[threadIdx.x >> 6] = sum;
  __syncthreads();
  if (threadIdx.x == 0) den[q] = red[0] + red[1] + red[2] + red[3];
}

// ---------------------------------------------------------------------------
// Gated combine: comb[t][c] = g0*attn1 + g1*rrp + g2*jan/den ; c = h*64+d
// ---------------------------------------------------------------------------
__global__ __launch_bounds__(256) void combine_kernel(
    const float* __restrict__ a1, const float* __restrict__ a2,
    const float* __restrict__ jraw, const float* __restrict__ denj,
    const float* __restrict__ gate, float* __restrict__ comb, int T)
{
  const int idx = blockIdx.x * 256 + threadIdx.x;
  const int t = idx >> 10;        // /E (=1024)
  const int c = idx & 1023;
  const int h = c >> 6;
  const int d = c & 63;
  float g0 = gate[h * 3 + 0], g1 = gate[h * 3 + 1], g2 = gate[h * 3 + 2];
  float mg = fmaxf(g0, fmaxf(g1, g2));
  float e0 = __expf(g0 - mg), e1 = __expf(g1 - mg), e2 = __expf(g2 - mg);
  float inv = 1.f / (e0 + e1 + e2);
  const size_t hd = ((size_t)h * T + t) * 64 + d;
  float v = (e0 * a1[hd] + e1 * a2[hd] + e2 * jraw[idx] / denj[t]) * inv;
  comb[idx] = v;
}

// ---------------------------------------------------------------------------
extern "C" void kernel_launch(void* const* d_in, const int* in_sizes, int n_in,
                              void* d_out, int out_size, void* d_ws, size_t ws_size,
                              hipStream_t stream)
{
  (void)in_sizes; (void)n_in; (void)out_size; (void)ws_size;
  const float* x    = (const float*)d_in[0];
  const float* wq   = (const float*)d_in[1];
  const float* wk   = (const float*)d_in[2];
  const float* wv   = (const float*)d_in[3];
  const float* wr   = (const float*)d_in[4];
  const float* wvr  = (const float*)d_in[5];
  const float* wj   = (const float*)d_in[6];
  const float* gate = (const float*)d_in[7];
  const float* wo   = (const float*)d_in[8];
  float* out = (float*)d_out;

  const int T = TT, E = EE, H = HH;
  const size_t TE = (size_t)T * E;

  float* ws = (float*)d_ws;
  float* qb    = ws;            // (H,T,64)
  float* kb    = qb + TE;       // (H,T,64)
  float* vb    = kb + TE;       // (H,T,64)
  float* rvb   = vb + TE;       // (H,T,64)
  float* echo  = rvb + TE;      // (T,E)
  float* echob = echo + TE;     // (T,E)
  float* attn1 = echob + TE;    // (H,T,64)
  float* attn2 = attn1 + TE;    // (H,T,64)
  float* Wj    = attn2 + TE;    // (T,T)
  float* rbuf  = Wj + (size_t)T * T;   // (H,T)
  float* wbuf  = rbuf + (size_t)H * T; // (H,T)
  float* sbuf  = wbuf + (size_t)H * T; // (T)
  float* denj  = sbuf + T;             // (T)
  // reuse: qb free after flash, kb free after flash
  float* jraw = qb;   // (T,E), written after flash
  float* comb = kb;   // (T,E), written after flash

  dim3 gProj(E / 64, T / 64);        // 16 x 32
  dim3 gJan(E / 64, T / 64);
  dim3 blk(256);

  // projections
  gemm64<true, 1><<<gProj, blk, 0, stream>>>(x, wq, qb, T, E, E);
  gemm64<true, 1><<<gProj, blk, 0, stream>>>(x, wk, kb, T, E, E);
  gemm64<true, 1><<<gProj, blk, 0, stream>>>(x, wv, vb, T, E, E);
  gemm64<true, 1><<<gProj, blk, 0, stream>>>(x, wvr, rvb, T, E, E);
  gemm64<true, 0><<<gProj, blk, 0, stream>>>(x, wj, echo, T, E, E);
  gemm64<false, 0><<<gProj, blk, 0, stream>>>(echo, wj, echob, T, E, E);

  // branch-2 scores
  rscore_kernel<<<dim3(T / 256, H), blk, 0, stream>>>(x, wr, rbuf, T, E);
  rsoftmax_kernel<<<H, blk, 0, stream>>>(rbuf, wbuf, T);

  // branch-3 scores
  sscore_kernel<<<T, blk, 0, stream>>>(x, echob, sbuf, E);

  // branch 1: flash attention
  flash_qkv<<<dim3(H, T / 64), blk, 0, stream>>>(qb, kb, vb, attn1, T);

  // branch 2: prefix scan
  rrp_scan_kernel<<<H, dim3(64), 0, stream>>>(wbuf, rvb, attn2, T);

  // branch 3: W matrix + GEMM (unnormalized; combine divides by den)
  janus_w_kernel<<<T, blk, 0, stream>>>(sbuf, Wj, denj, T);
  gemm64<false, 0><<<gJan, blk, 0, stream>>>(Wj, echo, jraw, T, E, T);

  // gated combine
  combine_kernel<<<(int)(TE / 256), blk, 0, stream>>>(attn1, attn2, jraw, denj,
                                                      gate, comb, T);

  // output projection
  gemm64<true, 0><<<gProj, blk, 0, stream>>>(comb, wo, out, T, E, E);
}

// Round 2
// 1229.537 us; speedup vs baseline: 2.2348x; 2.2348x over previous
//
#include <hip/hip_runtime.h>
#include <cstddef>

#define TT 2048
#define EE 1024
#define HH 16

typedef unsigned short ushort;
typedef unsigned int uint;
typedef __attribute__((ext_vector_type(8))) short short8;
typedef __attribute__((ext_vector_type(8))) _Float16 half8;
typedef __attribute__((ext_vector_type(4))) float f32x4;
typedef __attribute__((ext_vector_type(4))) ushort ushort4v;

__device__ __forceinline__ ushort f2bf(float f) {
  uint u = __builtin_bit_cast(uint, f);
  u = (u + 0x7FFFu + ((u >> 16) & 1u)) >> 16;
  return (ushort)u;
}
__device__ __forceinline__ float bf2f(ushort h) {
  return __builtin_bit_cast(float, (uint)h << 16);
}

// ---------------------------------------------------------------------------
// Conversions
// ---------------------------------------------------------------------------
__global__ __launch_bounds__(256) void cvt_bf16_k(
    const float* __restrict__ in, ushort* __restrict__ out, int n) {
  int i = (blockIdx.x * 256 + threadIdx.x) * 4;
  if (i >= n) return;
  float4 v = *(const float4*)(in + i);
  ushort4v o;
  o.x = f2bf(v.x); o.y = f2bf(v.y); o.z = f2bf(v.z); o.w = f2bf(v.w);
  *(ushort4v*)(out + i) = o;
}

__global__ __launch_bounds__(256) void cvt_f16_k(
    const float* __restrict__ in, ushort* __restrict__ out, int n) {
  int i = (blockIdx.x * 256 + threadIdx.x) * 4;
  if (i >= n) return;
  float4 v = *(const float4*)(in + i);
  ushort4v o;
  o.x = __builtin_bit_cast(ushort, (_Float16)v.x);
  o.y = __builtin_bit_cast(ushort, (_Float16)v.y);
  o.z = __builtin_bit_cast(ushort, (_Float16)v.z);
  o.w = __builtin_bit_cast(ushort, (_Float16)v.w);
  *(ushort4v*)(out + i) = o;
}

__global__ __launch_bounds__(256) void zero_k(float* __restrict__ p, int n) {
  int i = blockIdx.x * 256 + threadIdx.x;
  if (i < n) p[i] = 0.f;
}

// ---------------------------------------------------------------------------
// bf16/f16 MFMA GEMM: C = A @ B^T.  A:(M,K) row-major, B:(N,K) row-major,
// both 16-bit (ushort bit patterns). 128x128 tile, BK=32, 256 thr = 4 waves,
// wave = 64x64 via 4x4 grid of 16x16x32 mfma.
// IT: 0=bf16, 1=f16.
// OM: 0 = fp32 row-major (M,N)
//     1 = bf16 head layout  out[((c>>6)*M + m)*64 + (c&63)]      (H,M,64)
//     2 = bf16 headT layout out[(c>>6)*64*M + (c&63)*M + m]      (H,64,M)
//     3 = bf16 transposed   out[c*M + m]  + atomicAdd row norms to snorm
// CZ: causal A — A[m][k]==0 for k>m, so skip k0 >= m0+128.
// ---------------------------------------------------------------------------
template<int IT, int OM, bool CZ>
__global__ __launch_bounds__(256) void gemm_mfma(
    const ushort* __restrict__ A, const ushort* __restrict__ B,
    void* __restrict__ Cp, float* __restrict__ snorm, int M, int N, int K)
{
  __shared__ __align__(16) ushort As[128 * 32];
  __shared__ __align__(16) ushort Bs[128 * 32];
  const int tid = threadIdx.x;
  const int m0 = blockIdx.y * 128, n0 = blockIdx.x * 128;
  const int w = tid >> 6, lane = tid & 63;
  const int wr = w >> 1, wc = w & 1;
  const int lr = lane & 15, lk = lane >> 4;
  const int srow = tid >> 1, sk = (tid & 1) * 16;
  const ushort* Ag = A + (size_t)(m0 + srow) * K + sk;
  const ushort* Bg = B + (size_t)(n0 + srow) * K + sk;
  f32x4 acc[4][4] = {};
  const int Keff = CZ ? (K < m0 + 128 ? K : m0 + 128) : K;
  for (int k0 = 0; k0 < Keff; k0 += 32) {
    short8 av0 = *(const short8*)(Ag + k0);
    short8 av1 = *(const short8*)(Ag + k0 + 8);
    short8 bv0 = *(const short8*)(Bg + k0);
    short8 bv1 = *(const short8*)(Bg + k0 + 8);
    __syncthreads();
    *(short8*)(As + srow * 32 + sk) = av0;
    *(short8*)(As + srow * 32 + sk + 8) = av1;
    *(short8*)(Bs + srow * 32 + sk) = bv0;
    *(short8*)(Bs + srow * 32 + sk + 8) = bv1;
    __syncthreads();
    short8 af[4], bf[4];
#pragma unroll
    for (int i = 0; i < 4; ++i)
      af[i] = *(const short8*)(As + (wr * 64 + i * 16 + lr) * 32 + lk * 8);
#pragma unroll
    for (int j = 0; j < 4; ++j)
      bf[j] = *(const short8*)(Bs + (wc * 64 + j * 16 + lr) * 32 + lk * 8);
#pragma unroll
    for (int i = 0; i < 4; ++i)
#pragma unroll
      for (int j = 0; j < 4; ++j) {
        if (IT == 0)
          acc[i][j] = __builtin_amdgcn_mfma_f32_16x16x32_bf16(
              af[i], bf[j], acc[i][j], 0, 0, 0);
        else
          acc[i][j] = __builtin_amdgcn_mfma_f32_16x16x32_f16(
              __builtin_bit_cast(half8, af[i]), __builtin_bit_cast(half8, bf[j]),
              acc[i][j], 0, 0, 0);
      }
  }
  // epilogue: C/D layout col=lane&15, row=(lane>>4)*4+reg
#pragma unroll
  for (int i = 0; i < 4; ++i)
#pragma unroll
    for (int r = 0; r < 4; ++r) {
      int row = m0 + wr * 64 + i * 16 + lk * 4 + r;
#pragma unroll
      for (int j = 0; j < 4; ++j) {
        int col = n0 + wc * 64 + j * 16 + lr;
        float v = acc[i][j][r];
        if (OM == 0)
          ((float*)Cp)[(size_t)row * N + col] = v;
        else if (OM == 1)
          ((ushort*)Cp)[((size_t)(col >> 6) * M + row) * 64 + (col & 63)] = f2bf(v);
        else if (OM == 2)
          ((ushort*)Cp)[(size_t)(col >> 6) * 64 * M + (size_t)(col & 63) * M + row] = f2bf(v);
        else
          ((ushort*)Cp)[(size_t)col * M + row] = f2bf(v);
      }
    }
  if (OM == 3) {
#pragma unroll
    for (int i = 0; i < 4; ++i)
#pragma unroll
      for (int r = 0; r < 4; ++r) {
        float p = 0.f;
#pragma unroll
        for (int j = 0; j < 4; ++j) p += acc[i][j][r] * acc[i][j][r];
        p += __shfl_xor(p, 1); p += __shfl_xor(p, 2);
        p += __shfl_xor(p, 4); p += __shfl_xor(p, 8);
        if (lr == 0)
          atomicAdd(&snorm[m0 + wr * 64 + i * 16 + lk * 4 + r], p);
      }
  }
}

// ---------------------------------------------------------------------------
// Flash attention, bf16 MFMA. Q,K in (H,T,64) bf16; V pre-transposed (H,64,T).
// Block = (head, 64 q rows); 4 waves, wave w owns q rows q0+w*16..+15.
// ---------------------------------------------------------------------------
__global__ __launch_bounds__(256) void flash_mfma(
    const ushort* __restrict__ Qg, const ushort* __restrict__ Kg,
    const ushort* __restrict__ Vg, ushort* __restrict__ O, int T, int nqt)
{
  const int h = blockIdx.x;
  const int qt = nqt - 1 - blockIdx.y;  // heavy blocks first
  const int q0 = qt * 64;
  const int tid = threadIdx.x, w = tid >> 6, lane = tid & 63;
  const int lr = lane & 15, lk = lane >> 4;
  const ushort* Q = Qg + (size_t)h * T * 64;
  const ushort* K = Kg + (size_t)h * T * 64;
  const ushort* V = Vg + (size_t)h * 64 * T;
  __shared__ __align__(16) ushort Ps[4][16 * 72];

  short8 qa0 = *(const short8*)(Q + (size_t)(q0 + w * 16 + lr) * 64 + lk * 8);
  short8 qa1 = *(const short8*)(Q + (size_t)(q0 + w * 16 + lr) * 64 + 32 + lk * 8);
  f32x4 o[4] = {};
  float mr[4], lsum[4];
#pragma unroll
  for (int r = 0; r < 4; ++r) { mr[r] = -1e30f; lsum[r] = 0.f; }

  for (int kt = 0; kt <= qt; ++kt) {
    const int k0 = kt * 64;
    f32x4 s[4];
#pragma unroll
    for (int c = 0; c < 4; ++c) {
      const ushort* kp = K + (size_t)(k0 + c * 16 + lr) * 64 + lk * 8;
      short8 kb0 = *(const short8*)(kp);
      short8 kb1 = *(const short8*)(kp + 32);
      f32x4 z = {};
      z = __builtin_amdgcn_mfma_f32_16x16x32_bf16(qa0, kb0, z, 0, 0, 0);
      z = __builtin_amdgcn_mfma_f32_16x16x32_bf16(qa1, kb1, z, 0, 0, 0);
      s[c] = z;
    }
    const bool diag = (kt == qt);
    float rmax[4];
#pragma unroll
    for (int r = 0; r < 4; ++r) rmax[r] = -1e30f;
#pragma unroll
    for (int c = 0; c < 4; ++c)
#pragma unroll
      for (int r = 0; r < 4; ++r) {
        float v = s[c][r] * 0.125f;
        if (diag && (k0 + c * 16 + lr) > (q0 + w * 16 + lk * 4 + r)) v = -1e30f;
        s[c][r] = v;
        rmax[r] = fmaxf(rmax[r], v);
      }
#pragma unroll
    for (int r = 0; r < 4; ++r) {
      rmax[r] = fmaxf(rmax[r], __shfl_xor(rmax[r], 1));
      rmax[r] = fmaxf(rmax[r], __shfl_xor(rmax[r], 2));
      rmax[r] = fmaxf(rmax[r], __shfl_xor(rmax[r], 4));
      rmax[r] = fmaxf(rmax[r], __shfl_xor(rmax[r], 8));
    }
    float alpha[4];
#pragma unroll
    for (int r = 0; r < 4; ++r) {
      float mn = fmaxf(mr[r], rmax[r]);
      alpha[r] = __expf(mr[r] - mn);
      mr[r] = mn;
    }
    float rs[4] = {0.f, 0.f, 0.f, 0.f};
#pragma unroll
    for (int c = 0; c < 4; ++c)
#pragma unroll
      for (int r = 0; r < 4; ++r) {
        float p = __expf(s[c][r] - mr[r]);
        s[c][r] = p;
        rs[r] += p;
      }
#pragma unroll
    for (int r = 0; r < 4; ++r) {
      rs[r] += __shfl_xor(rs[r], 1);
      rs[r] += __shfl_xor(rs[r], 2);
      rs[r] += __shfl_xor(rs[r], 4);
      rs[r] += __shfl_xor(rs[r], 8);
      lsum[r] = lsum[r] * alpha[r] + rs[r];
    }
#pragma unroll
    for (int c = 0; c < 4; ++c)
#pragma unroll
      for (int r = 0; r < 4; ++r) o[c][r] *= alpha[r];
    // P: C-layout -> LDS -> A-layout (per-wave private region, no barrier)
#pragma unroll
    for (int c = 0; c < 4; ++c)
#pragma unroll
      for (int r = 0; r < 4; ++r)
        Ps[w][(lk * 4 + r) * 72 + c * 16 + lr] = f2bf(s[c][r]);
    short8 pa0 = *(const short8*)(&Ps[w][lr * 72 + lk * 8]);
    short8 pa1 = *(const short8*)(&Ps[w][lr * 72 + 32 + lk * 8]);
#pragma unroll
    for (int c = 0; c < 4; ++c) {
      const ushort* vp = V + (size_t)(c * 16 + lr) * T + k0 + lk * 8;
      short8 vb0 = *(const short8*)(vp);
      short8 vb1 = *(const short8*)(vp + 32);
      o[c] = __builtin_amdgcn_mfma_f32_16x16x32_bf16(pa0, vb0, o[c], 0, 0, 0);
      o[c] = __builtin_amdgcn_mfma_f32_16x16x32_bf16(pa1, vb1, o[c], 0, 0, 0);
    }
  }
  ushort* Oh = O + (size_t)h * T * 64;
#pragma unroll
  for (int c = 0; c < 4; ++c)
#pragma unroll
    for (int r = 0; r < 4; ++r) {
      int row = q0 + w * 16 + lk * 4 + r;
      Oh[(size_t)row * 64 + c * 16 + lr] = f2bf(o[c][r] / lsum[r]);
    }
}

// ---------------------------------------------------------------------------
// Branch 2: r[h][t] = sum_e x[t][e]*wr[h][e][t]  (fp32, memory-streaming)
// ---------------------------------------------------------------------------
__global__ __launch_bounds__(256) void rscore_kernel(
    const float* __restrict__ x, const float* __restrict__ wr,
    float* __restrict__ r, int T, int E)
{
  const int h = blockIdx.y;
  const int t = blockIdx.x * 256 + threadIdx.x;
  const float* wrh = wr + (size_t)h * E * T;
  float acc = 0.f;
  for (int e = 0; e < E; ++e)
    acc += x[(size_t)t * E + e] * wrh[(size_t)e * T + t];
  r[(size_t)h * T + t] = acc;
}

__global__ __launch_bounds__(256) void rsoftmax_kernel(
    const float* __restrict__ r, float* __restrict__ w, int T)
{
  const int h = blockIdx.x;
  const float* rh = r + (size_t)h * T;
  float mx = -1e30f;
  for (int t = threadIdx.x; t < T; t += 256) mx = fmaxf(mx, rh[t]);
#pragma unroll
  for (int o = 32; o; o >>= 1) mx = fmaxf(mx, __shfl_xor(mx, o));
  __shared__ float red[4];
  if ((threadIdx.x & 63) == 0) red[threadIdx.x >> 6] = mx;
  __syncthreads();
  mx = fmaxf(fmaxf(red[0], red[1]), fmaxf(red[2], red[3]));
  float* wh = w + (size_t)h * T;
  for (int t = threadIdx.x; t < T; t += 256)
    wh[t] = __expf((rh[t] - mx) * 0.125f);
}

// prefix weighted average, 4-segment two-pass. rv bf16 (H,T,64), out bf16.
__global__ __launch_bounds__(256) void rrp_scan(
    const float* __restrict__ wgt, const ushort* __restrict__ rv,
    ushort* __restrict__ out, int T)
{
  const int h = blockIdx.x;
  const int d = threadIdx.x & 63, seg = threadIdx.x >> 6;
  const int segLen = T / 4;
  const float* wh = wgt + (size_t)h * T;
  const ushort* rvh = rv + (size_t)h * T * 64;
  ushort* oh = out + (size_t)h * T * 64;
  const int kbeg = seg * segLen, kend = kbeg + segLen;
  float num = 0.f, den = 0.f;
  for (int k = kbeg; k < kend; ++k) {
    float wk = wh[k];
    num += wk * bf2f(rvh[(size_t)k * 64 + d]);
    den += wk;
  }
  __shared__ float sn[4][64];
  __shared__ float sd[4];
  sn[seg][d] = num;
  if (d == 0) sd[seg] = den;
  __syncthreads();
  float cn = 0.f, cd = 0.f;
  for (int s2 = 0; s2 < seg; ++s2) { cn += sn[s2][d]; cd += sd[s2]; }
  num = cn; den = cd;
  for (int k = kbeg; k < kend; ++k) {
    float wk = wh[k];
    num += wk * bf2f(rvh[(size_t)k * 64 + d]);
    den += wk;
    oh[(size_t)k * 64 + d] = f2bf(num / den);
  }
}

// ---------------------------------------------------------------------------
// Branch 3: W[q][k] (bf16) + row denominators. s_t = snorm[t]/32.
// ---------------------------------------------------------------------------
__global__ __launch_bounds__(256) void janus_w(
    const float* __restrict__ snorm, ushort* __restrict__ Wb,
    float* __restrict__ den, int T)
{
  const int q = blockIdx.x;
  const float sq = snorm[q] * 0.03125f;
  float mx = -1e30f;
  for (int k = threadIdx.x; k <= q; k += 256)
    mx = fmaxf(mx, sq * (snorm[k] * 0.03125f));
#pragma unroll
  for (int o = 32; o; o >>= 1) mx = fmaxf(mx, __shfl_xor(mx, o));
  __shared__ float red[4];
  if ((threadIdx.x & 63) == 0) red[threadIdx.x >> 6] = mx;
  __syncthreads();
  mx = fmaxf(fmaxf(red[0], red[1]), fmaxf(red[2], red[3]));
  float sum = 0.f;
  ushort* Wq = Wb + (size_t)q * T;
  for (int k = threadIdx.x; k < T; k += 256) {
    float wv = (k <= q) ? __expf(sq * (snorm[k] * 0.03125f) - mx) : 0.f;
    ushort wb = f2bf(wv);
    Wq[k] = wb;
    sum += bf2f(wb);  // match numerator's bf16 rounding
  }
#pragma unroll
  for (int o = 32; o; o >>= 1) sum += __shfl_xor(sum, o);
  __syncthreads();
  if ((threadIdx.x & 63) == 0) red[threadIdx.x >> 6] = sum;
  __syncthreads();
  if (threadIdx.x == 0) den[q] = red[0] + red[1] + red[2] + red[3];
}

// ---------------------------------------------------------------------------
// Gated combine -> comb bf16 (T,E)
// ---------------------------------------------------------------------------
__global__ __launch_bounds__(256) void combine_kernel(
    const ushort* __restrict__ a1, const ushort* __restrict__ a2,
    const float* __restrict__ jraw, const float* __restrict__ denj,
    const float* __restrict__ gate, ushort* __restrict__ comb, int T)
{
  const int idx = blockIdx.x * 256 + threadIdx.x;
  const int t = idx >> 10;
  const int c = idx & 1023;
  const int h = c >> 6;
  const int d = c & 63;
  float g0 = gate[h * 3 + 0], g1 = gate[h * 3 + 1], g2 = gate[h * 3 + 2];
  float mg = fmaxf(g0, fmaxf(g1, g2));
  float e0 = __expf(g0 - mg), e1 = __expf(g1 - mg), e2 = __expf(g2 - mg);
  float inv = 1.f / (e0 + e1 + e2);
  const size_t hd = ((size_t)h * T + t) * 64 + d;
  float v = (e0 * bf2f(a1[hd]) + e1 * bf2f(a2[hd]) + e2 * jraw[idx] / denj[t]) * inv;
  comb[idx] = f2bf(v);
}

// ---------------------------------------------------------------------------
extern "C" void kernel_launch(void* const* d_in, const int* in_sizes, int n_in,
                              void* d_out, int out_size, void* d_ws, size_t ws_size,
                              hipStream_t stream)
{
  (void)in_sizes; (void)n_in; (void)out_size; (void)ws_size;
  const float* x    = (const float*)d_in[0];
  const float* wq   = (const float*)d_in[1];
  const float* wk   = (const float*)d_in[2];
  const float* wv   = (const float*)d_in[3];
  const float* wr   = (const float*)d_in[4];
  const float* wvr  = (const float*)d_in[5];
  const float* wj   = (const float*)d_in[6];
  const float* gate = (const float*)d_in[7];
  const float* wo   = (const float*)d_in[8];
  float* out = (float*)d_out;

  const int T = TT, E = EE, H = HH;
  const size_t TE = (size_t)T * E;      // 2,097,152
  const size_t EE2 = (size_t)E * E;     // 1,048,576
  const size_t TT2 = (size_t)T * T;     // 4,194,304

  ushort* u = (ushort*)d_ws;
  ushort* xbf   = u;
  ushort* xh    = xbf + TE;
  ushort* wqb   = xh + TE;
  ushort* wkb   = wqb + EE2;
  ushort* wvb   = wkb + EE2;
  ushort* wvrb  = wvb + EE2;
  ushort* wob   = wvrb + EE2;
  ushort* wjh   = wob + EE2;
  ushort* qhb   = wjh + EE2;      // (H,T,64) bf16
  ushort* khb   = qhb + TE;       // (H,T,64) bf16
  ushort* vtb   = khb + TE;       // (H,64,T) bf16
  ushort* rvhb  = vtb + TE;       // (H,T,64) bf16
  ushort* echoT = rvhb + TE;      // (E,T)    bf16
  ushort* a1b   = echoT + TE;     // (H,T,64) bf16
  ushort* a2b   = a1b + TE;       // (H,T,64) bf16
  ushort* Wbf   = a2b + TE;       // (T,T)    bf16
  ushort* combb = Wbf + TT2;      // (T,E)    bf16
  float* jraw  = (float*)(combb + TE);  // (T,E) fp32
  float* rbuf  = jraw + TE;             // (H,T)
  float* wwb   = rbuf + (size_t)H * T;  // (H,T)
  float* snorm = wwb + (size_t)H * T;   // (T)
  float* denj  = snorm + T;             // (T)

  dim3 blk(256);
  // conversions
  cvt_bf16_k<<<(int)(TE / 1024), blk, 0, stream>>>(x, xbf, (int)TE);
  cvt_f16_k <<<(int)(TE / 1024), blk, 0, stream>>>(x, xh, (int)TE);
  cvt_bf16_k<<<(int)(EE2 / 1024), blk, 0, stream>>>(wq, wqb, (int)EE2);
  cvt_bf16_k<<<(int)(EE2 / 1024), blk, 0, stream>>>(wk, wkb, (int)EE2);
  cvt_bf16_k<<<(int)(EE2 / 1024), blk, 0, stream>>>(wv, wvb, (int)EE2);
  cvt_bf16_k<<<(int)(EE2 / 1024), blk, 0, stream>>>(wvr, wvrb, (int)EE2);
  cvt_bf16_k<<<(int)(EE2 / 1024), blk, 0, stream>>>(wo, wob, (int)EE2);
  cvt_f16_k <<<(int)(EE2 / 1024), blk, 0, stream>>>(wj, wjh, (int)EE2);
  zero_k<<<T / 256, blk, 0, stream>>>(snorm, T);

  // projections (MFMA)
  dim3 gP(E / 128, T / 128);  // (8,16)
  gemm_mfma<0, 1, false><<<gP, blk, 0, stream>>>(xbf, wqb, qhb, nullptr, T, E, E);
  gemm_mfma<0, 1, false><<<gP, blk, 0, stream>>>(xbf, wkb, khb, nullptr, T, E, E);
  gemm_mfma<0, 2, false><<<gP, blk, 0, stream>>>(xbf, wvb, vtb, nullptr, T, E, E);
  gemm_mfma<0, 1, false><<<gP, blk, 0, stream>>>(xbf, wvrb, rvhb, nullptr, T, E, E);
  // echo in fp16 (janus s-path precision), epilogue: echoT bf16 + row norms
  gemm_mfma<1, 3, false><<<gP, blk, 0, stream>>>(xh, wjh, echoT, snorm, T, E, E);

  // branch 2 scores
  rscore_kernel<<<dim3(T / 256, H), blk, 0, stream>>>(x, wr, rbuf, T, E);
  rsoftmax_kernel<<<H, blk, 0, stream>>>(rbuf, wwb, T);

  // branch 1: flash MFMA
  flash_mfma<<<dim3(H, T / 64), blk, 0, stream>>>(qhb, khb, vtb, a1b, T, T / 64);

  // branch 2: prefix scan
  rrp_scan<<<H, blk, 0, stream>>>(wwb, rvhb, a2b, T);

  // branch 3: W + causal GEMM (jraw = W @ echo, unnormalized)
  janus_w<<<T, blk, 0, stream>>>(snorm, Wbf, denj, T);
  gemm_mfma<0, 0, true><<<dim3(E / 128, T / 128), blk, 0, stream>>>(
      Wbf, echoT, jraw, nullptr, T, E, T);

  // combine + output projection
  combine_kernel<<<(int)(TE / 256), blk, 0, stream>>>(a1b, a2b, jraw, denj,
                                                      gate, combb, T);
  gemm_mfma<0, 0, false><<<gP, blk, 0, stream>>>(combb, wob, out, nullptr, T, E, E);
}

// Round 3
// 665.774 us; speedup vs baseline: 4.1272x; 1.8468x over previous
//
#include <hip/hip_runtime.h>
#include <cstddef>

#define TT 2048
#define EE 1024
#define HH 16

typedef unsigned short ushort;
typedef unsigned int uint;
typedef __attribute__((ext_vector_type(8))) short short8;
typedef __attribute__((ext_vector_type(8))) _Float16 half8;
typedef __attribute__((ext_vector_type(4))) float f32x4;
typedef __attribute__((ext_vector_type(4))) ushort ushort4v;

__device__ __forceinline__ ushort f2bf(float f) {
  uint u = __builtin_bit_cast(uint, f);
  u = (u + 0x7FFFu + ((u >> 16) & 1u)) >> 16;
  return (ushort)u;
}
__device__ __forceinline__ float bf2f(ushort h) {
  return __builtin_bit_cast(float, (uint)h << 16);
}

// ---------------------------------------------------------------------------
// Fused conversions
// ---------------------------------------------------------------------------
// x -> bf16 and f16 in one pass
__global__ __launch_bounds__(256) void cvt_x_k(
    const float* __restrict__ in, ushort* __restrict__ obf,
    ushort* __restrict__ oh, int n) {
  int i = (blockIdx.x * 256 + threadIdx.x) * 4;
  if (i >= n) return;
  float4 v = *(const float4*)(in + i);
  ushort4v b, h;
  b.x = f2bf(v.x); b.y = f2bf(v.y); b.z = f2bf(v.z); b.w = f2bf(v.w);
  h.x = __builtin_bit_cast(ushort, (_Float16)v.x);
  h.y = __builtin_bit_cast(ushort, (_Float16)v.y);
  h.z = __builtin_bit_cast(ushort, (_Float16)v.z);
  h.w = __builtin_bit_cast(ushort, (_Float16)v.w);
  *(ushort4v*)(obf + i) = b;
  *(ushort4v*)(oh + i) = h;
}

// 6 weight tensors in one launch; blockIdx.y selects. idx 5 (wj) -> f16.
__global__ __launch_bounds__(256) void cvt_w_k(
    const float* __restrict__ s0, const float* __restrict__ s1,
    const float* __restrict__ s2, const float* __restrict__ s3,
    const float* __restrict__ s4, const float* __restrict__ s5,
    ushort* __restrict__ d0, ushort* __restrict__ d1,
    ushort* __restrict__ d2, ushort* __restrict__ d3,
    ushort* __restrict__ d4, ushort* __restrict__ d5, int n) {
  const int which = blockIdx.y;
  const float* src; ushort* dst;
  switch (which) {
    case 0: src = s0; dst = d0; break;
    case 1: src = s1; dst = d1; break;
    case 2: src = s2; dst = d2; break;
    case 3: src = s3; dst = d3; break;
    case 4: src = s4; dst = d4; break;
    default: src = s5; dst = d5; break;
  }
  int i = (blockIdx.x * 256 + threadIdx.x) * 4;
  if (i >= n) return;
  float4 v = *(const float4*)(src + i);
  ushort4v o;
  if (which == 5) {
    o.x = __builtin_bit_cast(ushort, (_Float16)v.x);
    o.y = __builtin_bit_cast(ushort, (_Float16)v.y);
    o.z = __builtin_bit_cast(ushort, (_Float16)v.z);
    o.w = __builtin_bit_cast(ushort, (_Float16)v.w);
  } else {
    o.x = f2bf(v.x); o.y = f2bf(v.y); o.z = f2bf(v.z); o.w = f2bf(v.w);
  }
  *(ushort4v*)(dst + i) = o;
}

__global__ __launch_bounds__(256) void zero_k(float* __restrict__ p, int n) {
  int i = blockIdx.x * 256 + threadIdx.x;
  if (i < n) p[i] = 0.f;
}

// ---------------------------------------------------------------------------
// bf16/f16 MFMA GEMM: C = A @ B^T. 128x128 tile, BK=32, 256 thr = 4 waves.
// IT: 0=bf16, 1=f16.
// OM: 0 fp32 (M,N); 1 bf16 (H,M,64); 2 bf16 (H,64,M); 3 bf16 (N,M) + row norms
// CZ: causal A (skip k0 >= m0+128)
// ---------------------------------------------------------------------------
template<int IT, int OM, bool CZ>
__global__ __launch_bounds__(256) void gemm_mfma(
    const ushort* __restrict__ A, const ushort* __restrict__ B,
    void* __restrict__ Cp, float* __restrict__ snorm, int M, int N, int K)
{
  __shared__ __align__(16) ushort As[128 * 32];
  __shared__ __align__(16) ushort Bs[128 * 32];
  const int tid = threadIdx.x;
  const int m0 = blockIdx.y * 128, n0 = blockIdx.x * 128;
  const int w = tid >> 6, lane = tid & 63;
  const int wr = w >> 1, wc = w & 1;
  const int lr = lane & 15, lk = lane >> 4;
  const int srow = tid >> 1, sk = (tid & 1) * 16;
  const ushort* Ag = A + (size_t)(m0 + srow) * K + sk;
  const ushort* Bg = B + (size_t)(n0 + srow) * K + sk;
  f32x4 acc[4][4] = {};
  const int Keff = CZ ? (K < m0 + 128 ? K : m0 + 128) : K;
  for (int k0 = 0; k0 < Keff; k0 += 32) {
    short8 av0 = *(const short8*)(Ag + k0);
    short8 av1 = *(const short8*)(Ag + k0 + 8);
    short8 bv0 = *(const short8*)(Bg + k0);
    short8 bv1 = *(const short8*)(Bg + k0 + 8);
    __syncthreads();
    *(short8*)(As + srow * 32 + sk) = av0;
    *(short8*)(As + srow * 32 + sk + 8) = av1;
    *(short8*)(Bs + srow * 32 + sk) = bv0;
    *(short8*)(Bs + srow * 32 + sk + 8) = bv1;
    __syncthreads();
    short8 af[4], bf[4];
#pragma unroll
    for (int i = 0; i < 4; ++i)
      af[i] = *(const short8*)(As + (wr * 64 + i * 16 + lr) * 32 + lk * 8);
#pragma unroll
    for (int j = 0; j < 4; ++j)
      bf[j] = *(const short8*)(Bs + (wc * 64 + j * 16 + lr) * 32 + lk * 8);
#pragma unroll
    for (int i = 0; i < 4; ++i)
#pragma unroll
      for (int j = 0; j < 4; ++j) {
        if (IT == 0)
          acc[i][j] = __builtin_amdgcn_mfma_f32_16x16x32_bf16(
              af[i], bf[j], acc[i][j], 0, 0, 0);
        else
          acc[i][j] = __builtin_amdgcn_mfma_f32_16x16x32_f16(
              __builtin_bit_cast(half8, af[i]), __builtin_bit_cast(half8, bf[j]),
              acc[i][j], 0, 0, 0);
      }
  }
#pragma unroll
  for (int i = 0; i < 4; ++i)
#pragma unroll
    for (int r = 0; r < 4; ++r) {
      int row = m0 + wr * 64 + i * 16 + lk * 4 + r;
#pragma unroll
      for (int j = 0; j < 4; ++j) {
        int col = n0 + wc * 64 + j * 16 + lr;
        float v = acc[i][j][r];
        if (OM == 0)
          ((float*)Cp)[(size_t)row * N + col] = v;
        else if (OM == 1)
          ((ushort*)Cp)[((size_t)(col >> 6) * M + row) * 64 + (col & 63)] = f2bf(v);
        else if (OM == 2)
          ((ushort*)Cp)[(size_t)(col >> 6) * 64 * M + (size_t)(col & 63) * M + row] = f2bf(v);
        else
          ((ushort*)Cp)[(size_t)col * M + row] = f2bf(v);
      }
    }
  if (OM == 3) {
#pragma unroll
    for (int i = 0; i < 4; ++i)
#pragma unroll
      for (int r = 0; r < 4; ++r) {
        float p = 0.f;
#pragma unroll
        for (int j = 0; j < 4; ++j) p += acc[i][j][r] * acc[i][j][r];
        p += __shfl_xor(p, 1); p += __shfl_xor(p, 2);
        p += __shfl_xor(p, 4); p += __shfl_xor(p, 8);
        if (lr == 0)
          atomicAdd(&snorm[m0 + wr * 64 + i * 16 + lk * 4 + r], p);
      }
  }
}

// ---------------------------------------------------------------------------
// Flash attention, bf16 MFMA (unchanged from round 2)
// ---------------------------------------------------------------------------
__global__ __launch_bounds__(256) void flash_mfma(
    const ushort* __restrict__ Qg, const ushort* __restrict__ Kg,
    const ushort* __restrict__ Vg, ushort* __restrict__ O, int T, int nqt)
{
  const int h = blockIdx.x;
  const int qt = nqt - 1 - blockIdx.y;
  const int q0 = qt * 64;
  const int tid = threadIdx.x, w = tid >> 6, lane = tid & 63;
  const int lr = lane & 15, lk = lane >> 4;
  const ushort* Q = Qg + (size_t)h * T * 64;
  const ushort* K = Kg + (size_t)h * T * 64;
  const ushort* V = Vg + (size_t)h * 64 * T;
  __shared__ __align__(16) ushort Ps[4][16 * 72];

  short8 qa0 = *(const short8*)(Q + (size_t)(q0 + w * 16 + lr) * 64 + lk * 8);
  short8 qa1 = *(const short8*)(Q + (size_t)(q0 + w * 16 + lr) * 64 + 32 + lk * 8);
  f32x4 o[4] = {};
  float mr[4], lsum[4];
#pragma unroll
  for (int r = 0; r < 4; ++r) { mr[r] = -1e30f; lsum[r] = 0.f; }

  for (int kt = 0; kt <= qt; ++kt) {
    const int k0 = kt * 64;
    f32x4 s[4];
#pragma unroll
    for (int c = 0; c < 4; ++c) {
      const ushort* kp = K + (size_t)(k0 + c * 16 + lr) * 64 + lk * 8;
      short8 kb0 = *(const short8*)(kp);
      short8 kb1 = *(const short8*)(kp + 32);
      f32x4 z = {};
      z = __builtin_amdgcn_mfma_f32_16x16x32_bf16(qa0, kb0, z, 0, 0, 0);
      z = __builtin_amdgcn_mfma_f32_16x16x32_bf16(qa1, kb1, z, 0, 0, 0);
      s[c] = z;
    }
    const bool diag = (kt == qt);
    float rmax[4];
#pragma unroll
    for (int r = 0; r < 4; ++r) rmax[r] = -1e30f;
#pragma unroll
    for (int c = 0; c < 4; ++c)
#pragma unroll
      for (int r = 0; r < 4; ++r) {
        float v = s[c][r] * 0.125f;
        if (diag && (k0 + c * 16 + lr) > (q0 + w * 16 + lk * 4 + r)) v = -1e30f;
        s[c][r] = v;
        rmax[r] = fmaxf(rmax[r], v);
      }
#pragma unroll
    for (int r = 0; r < 4; ++r) {
      rmax[r] = fmaxf(rmax[r], __shfl_xor(rmax[r], 1));
      rmax[r] = fmaxf(rmax[r], __shfl_xor(rmax[r], 2));
      rmax[r] = fmaxf(rmax[r], __shfl_xor(rmax[r], 4));
      rmax[r] = fmaxf(rmax[r], __shfl_xor(rmax[r], 8));
    }
    float alpha[4];
#pragma unroll
    for (int r = 0; r < 4; ++r) {
      float mn = fmaxf(mr[r], rmax[r]);
      alpha[r] = __expf(mr[r] - mn);
      mr[r] = mn;
    }
    float rs[4] = {0.f, 0.f, 0.f, 0.f};
#pragma unroll
    for (int c = 0; c < 4; ++c)
#pragma unroll
      for (int r = 0; r < 4; ++r) {
        float p = __expf(s[c][r] - mr[r]);
        s[c][r] = p;
        rs[r] += p;
      }
#pragma unroll
    for (int r = 0; r < 4; ++r) {
      rs[r] += __shfl_xor(rs[r], 1);
      rs[r] += __shfl_xor(rs[r], 2);
      rs[r] += __shfl_xor(rs[r], 4);
      rs[r] += __shfl_xor(rs[r], 8);
      lsum[r] = lsum[r] * alpha[r] + rs[r];
    }
#pragma unroll
    for (int c = 0; c < 4; ++c)
#pragma unroll
      for (int r = 0; r < 4; ++r) o[c][r] *= alpha[r];
#pragma unroll
    for (int c = 0; c < 4; ++c)
#pragma unroll
      for (int r = 0; r < 4; ++r)
        Ps[w][(lk * 4 + r) * 72 + c * 16 + lr] = f2bf(s[c][r]);
    short8 pa0 = *(const short8*)(&Ps[w][lr * 72 + lk * 8]);
    short8 pa1 = *(const short8*)(&Ps[w][lr * 72 + 32 + lk * 8]);
#pragma unroll
    for (int c = 0; c < 4; ++c) {
      const ushort* vp = V + (size_t)(c * 16 + lr) * T + k0 + lk * 8;
      short8 vb0 = *(const short8*)(vp);
      short8 vb1 = *(const short8*)(vp + 32);
      o[c] = __builtin_amdgcn_mfma_f32_16x16x32_bf16(pa0, vb0, o[c], 0, 0, 0);
      o[c] = __builtin_amdgcn_mfma_f32_16x16x32_bf16(pa1, vb1, o[c], 0, 0, 0);
    }
  }
  ushort* Oh = O + (size_t)h * T * 64;
#pragma unroll
  for (int c = 0; c < 4; ++c)
#pragma unroll
    for (int r = 0; r < 4; ++r) {
      int row = q0 + w * 16 + lk * 4 + r;
      Oh[(size_t)row * 64 + c * 16 + lr] = f2bf(o[c][r] / lsum[r]);
    }
}

// ---------------------------------------------------------------------------
// Branch 2: segmented r-score. grid (T/1024, H, 16); thread: 4 t, 64 e.
// rpart[(seg*H + h)*T + t] partials, summed in rsoftmax2.
// ---------------------------------------------------------------------------
__global__ __launch_bounds__(256) void rscore2(
    const float* __restrict__ x, const float* __restrict__ wr,
    float* __restrict__ rpart, int T, int E)
{
  const int h = blockIdx.y;
  const int e0 = blockIdx.z * 64;
  const int t0 = (blockIdx.x * 256 + threadIdx.x) * 4;
  const float* wrh = wr + (size_t)h * E * T;
  float4 acc = {0.f, 0.f, 0.f, 0.f};
  for (int e = e0; e < e0 + 64; ++e) {
    float4 w4 = *(const float4*)(wrh + (size_t)e * T + t0);
    acc.x += x[(size_t)(t0 + 0) * E + e] * w4.x;
    acc.y += x[(size_t)(t0 + 1) * E + e] * w4.y;
    acc.z += x[(size_t)(t0 + 2) * E + e] * w4.z;
    acc.w += x[(size_t)(t0 + 3) * E + e] * w4.w;
  }
  *(float4*)(rpart + ((size_t)blockIdx.z * HH + h) * T + t0) = acc;
}

__global__ __launch_bounds__(256) void rsoftmax2(
    const float* __restrict__ rpart, float* __restrict__ w, int T)
{
  const int h = blockIdx.x;
  __shared__ float rs[TT];
  __shared__ float red[4];
  for (int t = threadIdx.x; t < T; t += 256) {
    float a = 0.f;
#pragma unroll
    for (int s = 0; s < 16; ++s) a += rpart[((size_t)s * HH + h) * T + t];
    rs[t] = a;
  }
  __syncthreads();
  float mx = -1e30f;
  for (int t = threadIdx.x; t < T; t += 256) mx = fmaxf(mx, rs[t]);
#pragma unroll
  for (int o = 32; o; o >>= 1) mx = fmaxf(mx, __shfl_xor(mx, o));
  if ((threadIdx.x & 63) == 0) red[threadIdx.x >> 6] = mx;
  __syncthreads();
  mx = fmaxf(fmaxf(red[0], red[1]), fmaxf(red[2], red[3]));
  float* wh = w + (size_t)h * T;
  for (int t = threadIdx.x; t < T; t += 256)
    wh[t] = __expf((rs[t] - mx) * 0.125f);
}

// prefix weighted average, 32 segments, 8 d x 8 lanes per segment.
__global__ __launch_bounds__(256) void rrp_scan(
    const float* __restrict__ wgt, const ushort* __restrict__ rv,
    ushort* __restrict__ out, int T)
{
  const int h = blockIdx.x;
  const int seg = threadIdx.x >> 3;        // 0..31
  const int d0 = (threadIdx.x & 7) * 8;    // 0..56
  const int segLen = T >> 5;               // 64
  const float* wh = wgt + (size_t)h * T;
  const ushort* rvh = rv + (size_t)h * T * 64;
  ushort* oh = out + (size_t)h * T * 64;
  const int kbeg = seg * segLen, kend = kbeg + segLen;
  float num[8] = {};
  float den = 0.f;
  for (int k = kbeg; k < kend; ++k) {
    float wk = wh[k];
    short8 v = *(const short8*)(rvh + (size_t)k * 64 + d0);
#pragma unroll
    for (int j = 0; j < 8; ++j) num[j] += wk * bf2f((ushort)v[j]);
    den += wk;
  }
  __shared__ float sn[32][64];
  __shared__ float sd[32];
#pragma unroll
  for (int j = 0; j < 8; ++j) sn[seg][d0 + j] = num[j];
  if (d0 == 0) sd[seg] = den;
  __syncthreads();
  float cn[8] = {};
  float cd = 0.f;
  for (int s2 = 0; s2 < seg; ++s2) {
#pragma unroll
    for (int j = 0; j < 8; ++j) cn[j] += sn[s2][d0 + j];
    cd += sd[s2];
  }
  for (int k = kbeg; k < kend; ++k) {
    float wk = wh[k];
    short8 v = *(const short8*)(rvh + (size_t)k * 64 + d0);
    cd += wk;
#pragma unroll
    for (int j = 0; j < 8; ++j) cn[j] += wk * bf2f((ushort)v[j]);
    float inv = 1.f / cd;
    short8 o;
#pragma unroll
    for (int j = 0; j < 8; ++j) o[j] = (short)f2bf(cn[j] * inv);
    *(short8*)(oh + (size_t)k * 64 + d0) = o;
  }
}

// ---------------------------------------------------------------------------
// Branch 3: W[q][k] (bf16) + row denominators. s_t = snorm[t]/32.
// ---------------------------------------------------------------------------
__global__ __launch_bounds__(256) void janus_w(
    const float* __restrict__ snorm, ushort* __restrict__ Wb,
    float* __restrict__ den, int T)
{
  const int q = blockIdx.x;
  const float sq = snorm[q] * 0.03125f;
  float mx = -1e30f;
  for (int k = threadIdx.x; k <= q; k += 256)
    mx = fmaxf(mx, sq * (snorm[k] * 0.03125f));
#pragma unroll
  for (int o = 32; o; o >>= 1) mx = fmaxf(mx, __shfl_xor(mx, o));
  __shared__ float red[4];
  if ((threadIdx.x & 63) == 0) red[threadIdx.x >> 6] = mx;
  __syncthreads();
  mx = fmaxf(fmaxf(red[0], red[1]), fmaxf(red[2], red[3]));
  float sum = 0.f;
  ushort* Wq = Wb + (size_t)q * T;
  for (int k = threadIdx.x; k < T; k += 256) {
    float wv = (k <= q) ? __expf(sq * (snorm[k] * 0.03125f) - mx) : 0.f;
    ushort wb = f2bf(wv);
    Wq[k] = wb;
    sum += bf2f(wb);
  }
#pragma unroll
  for (int o = 32; o; o >>= 1) sum += __shfl_xor(sum, o);
  __syncthreads();
  if ((threadIdx.x & 63) == 0) red[threadIdx.x >> 6] = sum;
  __syncthreads();
  if (threadIdx.x == 0) den[q] = red[0] + red[1] + red[2] + red[3];
}

// ---------------------------------------------------------------------------
// Gated combine -> comb bf16 (T,E)
// ---------------------------------------------------------------------------
__global__ __launch_bounds__(256) void combine_kernel(
    const ushort* __restrict__ a1, const ushort* __restrict__ a2,
    const float* __restrict__ jraw, const float* __restrict__ denj,
    const float* __restrict__ gate, ushort* __restrict__ comb, int T)
{
  const int idx = blockIdx.x * 256 + threadIdx.x;
  const int t = idx >> 10;
  const int c = idx & 1023;
  const int h = c >> 6;
  const int d = c & 63;
  float g0 = gate[h * 3 + 0], g1 = gate[h * 3 + 1], g2 = gate[h * 3 + 2];
  float mg = fmaxf(g0, fmaxf(g1, g2));
  float e0 = __expf(g0 - mg), e1 = __expf(g1 - mg), e2 = __expf(g2 - mg);
  float inv = 1.f / (e0 + e1 + e2);
  const size_t hd = ((size_t)h * T + t) * 64 + d;
  float v = (e0 * bf2f(a1[hd]) + e1 * bf2f(a2[hd]) + e2 * jraw[idx] / denj[t]) * inv;
  comb[idx] = f2bf(v);
}

// ---------------------------------------------------------------------------
extern "C" void kernel_launch(void* const* d_in, const int* in_sizes, int n_in,
                              void* d_out, int out_size, void* d_ws, size_t ws_size,
                              hipStream_t stream)
{
  (void)in_sizes; (void)n_in; (void)out_size; (void)ws_size;
  const float* x    = (const float*)d_in[0];
  const float* wq   = (const float*)d_in[1];
  const float* wk   = (const float*)d_in[2];
  const float* wv   = (const float*)d_in[3];
  const float* wr   = (const float*)d_in[4];
  const float* wvr  = (const float*)d_in[5];
  const float* wj   = (const float*)d_in[6];
  const float* gate = (const float*)d_in[7];
  const float* wo   = (const float*)d_in[8];
  float* out = (float*)d_out;

  const int T = TT, E = EE, H = HH;
  const size_t TE = (size_t)T * E;      // 2,097,152
  const size_t EE2 = (size_t)E * E;     // 1,048,576
  const size_t TT2 = (size_t)T * T;     // 4,194,304

  ushort* u = (ushort*)d_ws;
  ushort* xbf   = u;
  ushort* xh    = xbf + TE;
  ushort* wqb   = xh + TE;
  ushort* wkb   = wqb + EE2;
  ushort* wvb   = wkb + EE2;
  ushort* wvrb  = wvb + EE2;
  ushort* wob   = wvrb + EE2;
  ushort* wjh   = wob + EE2;
  ushort* qhb   = wjh + EE2;      // (H,T,64) bf16
  ushort* khb   = qhb + TE;       // (H,T,64) bf16
  ushort* vtb   = khb + TE;       // (H,64,T) bf16
  ushort* rvhb  = vtb + TE;       // (H,T,64) bf16
  ushort* echoT = rvhb + TE;      // (E,T)    bf16
  ushort* a1b   = echoT + TE;     // (H,T,64) bf16
  ushort* a2b   = a1b + TE;       // (H,T,64) bf16
  ushort* Wbf   = a2b + TE;       // (T,T)    bf16
  ushort* combb = Wbf + TT2;      // (T,E)    bf16
  float* jraw  = (float*)(combb + TE);  // (T,E) fp32
  float* wwb   = jraw + TE;             // (H,T)
  float* snorm = wwb + (size_t)H * T;   // (T)
  float* denj  = snorm + T;             // (T)
  float* rpart = denj + T;              // (16,H,T) fp32 partials

  dim3 blk(256);
  // conversions (fused)
  cvt_x_k<<<(int)(TE / 1024), blk, 0, stream>>>(x, xbf, xh, (int)TE);
  cvt_w_k<<<dim3((int)(EE2 / 1024), 6), blk, 0, stream>>>(
      wq, wk, wv, wvr, wo, wj, wqb, wkb, wvb, wvrb, wob, wjh, (int)EE2);
  zero_k<<<T / 256, blk, 0, stream>>>(snorm, T);

  // projections (MFMA)
  dim3 gP(E / 128, T / 128);  // (8,16)
  gemm_mfma<0, 1, false><<<gP, blk, 0, stream>>>(xbf, wqb, qhb, nullptr, T, E, E);
  gemm_mfma<0, 1, false><<<gP, blk, 0, stream>>>(xbf, wkb, khb, nullptr, T, E, E);
  gemm_mfma<0, 2, false><<<gP, blk, 0, stream>>>(xbf, wvb, vtb, nullptr, T, E, E);
  gemm_mfma<0, 1, false><<<gP, blk, 0, stream>>>(xbf, wvrb, rvhb, nullptr, T, E, E);
  gemm_mfma<1, 3, false><<<gP, blk, 0, stream>>>(xh, wjh, echoT, snorm, T, E, E);

  // branch 2 scores (segmented, deterministic partials)
  rscore2<<<dim3(T / 1024, H, 16), blk, 0, stream>>>(x, wr, rpart, T, E);
  rsoftmax2<<<H, blk, 0, stream>>>(rpart, wwb, T);

  // branch 1: flash MFMA
  flash_mfma<<<dim3(H, T / 64), blk, 0, stream>>>(qhb, khb, vtb, a1b, T, T / 64);

  // branch 2: prefix scan
  rrp_scan<<<H, blk, 0, stream>>>(wwb, rvhb, a2b, T);

  // branch 3: W + causal GEMM
  janus_w<<<T, blk, 0, stream>>>(snorm, Wbf, denj, T);
  gemm_mfma<0, 0, true><<<dim3(E / 128, T / 128), blk, 0, stream>>>(
      Wbf, echoT, jraw, nullptr, T, E, T);

  // combine + output projection
  combine_kernel<<<(int)(TE / 256), blk, 0, stream>>>(a1b, a2b, jraw, denj,
                                                      gate, combb, T);
  gemm_mfma<0, 0, false><<<gP, blk, 0, stream>>>(combb, wob, out, nullptr, T, E, E);
}

// Round 4
// 571.267 us; speedup vs baseline: 4.8099x; 1.1654x over previous
//
#include <hip/hip_runtime.h>
#include <cstddef>

#define TT 2048
#define EE 1024
#define HH 16

typedef unsigned short ushort;
typedef unsigned int uint;
typedef __attribute__((ext_vector_type(8))) short short8;
typedef __attribute__((ext_vector_type(8))) _Float16 half8;
typedef __attribute__((ext_vector_type(4))) float f32x4;
typedef __attribute__((ext_vector_type(4))) ushort ushort4v;

__device__ __forceinline__ ushort f2bf(float f) {
  uint u = __builtin_bit_cast(uint, f);
  u = (u + 0x7FFFu + ((u >> 16) & 1u)) >> 16;
  return (ushort)u;
}
__device__ __forceinline__ float bf2f(ushort h) {
  return __builtin_bit_cast(float, (uint)h << 16);
}

// ---------------------------------------------------------------------------
// Conversions (fused). cvt_x also zeroes snorm (block 0).
// ---------------------------------------------------------------------------
__global__ __launch_bounds__(256) void cvt_x_k(
    const float* __restrict__ in, ushort* __restrict__ obf,
    ushort* __restrict__ oh, float* __restrict__ snorm, int n) {
  if (blockIdx.x == 0) {
    for (int i = threadIdx.x; i < TT; i += 256) snorm[i] = 0.f;
  }
  int i = (blockIdx.x * 256 + threadIdx.x) * 4;
  if (i >= n) return;
  float4 v = *(const float4*)(in + i);
  ushort4v b, h;
  b.x = f2bf(v.x); b.y = f2bf(v.y); b.z = f2bf(v.z); b.w = f2bf(v.w);
  h.x = __builtin_bit_cast(ushort, (_Float16)v.x);
  h.y = __builtin_bit_cast(ushort, (_Float16)v.y);
  h.z = __builtin_bit_cast(ushort, (_Float16)v.z);
  h.w = __builtin_bit_cast(ushort, (_Float16)v.w);
  *(ushort4v*)(obf + i) = b;
  *(ushort4v*)(oh + i) = h;
}

__global__ __launch_bounds__(256) void cvt_w_k(
    const float* __restrict__ s0, const float* __restrict__ s1,
    const float* __restrict__ s2, const float* __restrict__ s3,
    const float* __restrict__ s4, const float* __restrict__ s5,
    ushort* __restrict__ d0, ushort* __restrict__ d1,
    ushort* __restrict__ d2, ushort* __restrict__ d3,
    ushort* __restrict__ d4, ushort* __restrict__ d5, int n) {
  const int which = blockIdx.y;
  const float* src; ushort* dst;
  switch (which) {
    case 0: src = s0; dst = d0; break;
    case 1: src = s1; dst = d1; break;
    case 2: src = s2; dst = d2; break;
    case 3: src = s3; dst = d3; break;
    case 4: src = s4; dst = d4; break;
    default: src = s5; dst = d5; break;
  }
  int i = (blockIdx.x * 256 + threadIdx.x) * 4;
  if (i >= n) return;
  float4 v = *(const float4*)(src + i);
  ushort4v o;
  if (which == 5) {
    o.x = __builtin_bit_cast(ushort, (_Float16)v.x);
    o.y = __builtin_bit_cast(ushort, (_Float16)v.y);
    o.z = __builtin_bit_cast(ushort, (_Float16)v.z);
    o.w = __builtin_bit_cast(ushort, (_Float16)v.w);
  } else {
    o.x = f2bf(v.x); o.y = f2bf(v.y); o.z = f2bf(v.z); o.w = f2bf(v.w);
  }
  *(ushort4v*)(dst + i) = o;
}

// ---------------------------------------------------------------------------
// Merged 4-way projection GEMM: C_z = x @ W_z^T, z = blockIdx.z.
// z: 0=wq->qhb(OM1) 1=wk->khb(OM1) 2=wv->vtb(OM2) 3=wvr->rvhb(OM1)
// 128x128 tile, BK=32, bf16 MFMA.
// ---------------------------------------------------------------------------
__global__ __launch_bounds__(256) void proj4(
    const ushort* __restrict__ A,
    const ushort* __restrict__ B0, const ushort* __restrict__ B1,
    const ushort* __restrict__ B2, const ushort* __restrict__ B3,
    ushort* __restrict__ C0, ushort* __restrict__ C1,
    ushort* __restrict__ C2, ushort* __restrict__ C3,
    int M, int N, int K)
{
  const ushort* B; ushort* C; int om;
  switch (blockIdx.z) {
    case 0: B = B0; C = C0; om = 1; break;
    case 1: B = B1; C = C1; om = 1; break;
    case 2: B = B2; C = C2; om = 2; break;
    default: B = B3; C = C3; om = 1; break;
  }
  __shared__ __align__(16) ushort As[128 * 32];
  __shared__ __align__(16) ushort Bs[128 * 32];
  const int tid = threadIdx.x;
  const int m0 = blockIdx.y * 128, n0 = blockIdx.x * 128;
  const int w = tid >> 6, lane = tid & 63;
  const int wr = w >> 1, wc = w & 1;
  const int lr = lane & 15, lk = lane >> 4;
  const int srow = tid >> 1, sk = (tid & 1) * 16;
  const ushort* Ag = A + (size_t)(m0 + srow) * K + sk;
  const ushort* Bg = B + (size_t)(n0 + srow) * K + sk;
  f32x4 acc[4][4] = {};
  for (int k0 = 0; k0 < K; k0 += 32) {
    short8 av0 = *(const short8*)(Ag + k0);
    short8 av1 = *(const short8*)(Ag + k0 + 8);
    short8 bv0 = *(const short8*)(Bg + k0);
    short8 bv1 = *(const short8*)(Bg + k0 + 8);
    __syncthreads();
    *(short8*)(As + srow * 32 + sk) = av0;
    *(short8*)(As + srow * 32 + sk + 8) = av1;
    *(short8*)(Bs + srow * 32 + sk) = bv0;
    *(short8*)(Bs + srow * 32 + sk + 8) = bv1;
    __syncthreads();
    short8 af[4], bf[4];
#pragma unroll
    for (int i = 0; i < 4; ++i)
      af[i] = *(const short8*)(As + (wr * 64 + i * 16 + lr) * 32 + lk * 8);
#pragma unroll
    for (int j = 0; j < 4; ++j)
      bf[j] = *(const short8*)(Bs + (wc * 64 + j * 16 + lr) * 32 + lk * 8);
#pragma unroll
    for (int i = 0; i < 4; ++i)
#pragma unroll
      for (int j = 0; j < 4; ++j)
        acc[i][j] = __builtin_amdgcn_mfma_f32_16x16x32_bf16(
            af[i], bf[j], acc[i][j], 0, 0, 0);
  }
#pragma unroll
  for (int i = 0; i < 4; ++i)
#pragma unroll
    for (int r = 0; r < 4; ++r) {
      int row = m0 + wr * 64 + i * 16 + lk * 4 + r;
#pragma unroll
      for (int j = 0; j < 4; ++j) {
        int col = n0 + wc * 64 + j * 16 + lr;
        ushort v = f2bf(acc[i][j][r]);
        if (om == 1)
          C[((size_t)(col >> 6) * M + row) * 64 + (col & 63)] = v;
        else
          C[(size_t)(col >> 6) * 64 * M + (size_t)(col & 63) * M + row] = v;
      }
    }
}

// ---------------------------------------------------------------------------
// Generic MFMA GEMM (for echo / janus / out). Same as round 3.
// ---------------------------------------------------------------------------
template<int IT, int OM, bool CZ>
__global__ __launch_bounds__(256) void gemm_mfma(
    const ushort* __restrict__ A, const ushort* __restrict__ B,
    void* __restrict__ Cp, float* __restrict__ snorm, int M, int N, int K)
{
  __shared__ __align__(16) ushort As[128 * 32];
  __shared__ __align__(16) ushort Bs[128 * 32];
  const int tid = threadIdx.x;
  const int m0 = blockIdx.y * 128, n0 = blockIdx.x * 128;
  const int w = tid >> 6, lane = tid & 63;
  const int wr = w >> 1, wc = w & 1;
  const int lr = lane & 15, lk = lane >> 4;
  const int srow = tid >> 1, sk = (tid & 1) * 16;
  const ushort* Ag = A + (size_t)(m0 + srow) * K + sk;
  const ushort* Bg = B + (size_t)(n0 + srow) * K + sk;
  f32x4 acc[4][4] = {};
  const int Keff = CZ ? (K < m0 + 128 ? K : m0 + 128) : K;
  for (int k0 = 0; k0 < Keff; k0 += 32) {
    short8 av0 = *(const short8*)(Ag + k0);
    short8 av1 = *(const short8*)(Ag + k0 + 8);
    short8 bv0 = *(const short8*)(Bg + k0);
    short8 bv1 = *(const short8*)(Bg + k0 + 8);
    __syncthreads();
    *(short8*)(As + srow * 32 + sk) = av0;
    *(short8*)(As + srow * 32 + sk + 8) = av1;
    *(short8*)(Bs + srow * 32 + sk) = bv0;
    *(short8*)(Bs + srow * 32 + sk + 8) = bv1;
    __syncthreads();
    short8 af[4], bf[4];
#pragma unroll
    for (int i = 0; i < 4; ++i)
      af[i] = *(const short8*)(As + (wr * 64 + i * 16 + lr) * 32 + lk * 8);
#pragma unroll
    for (int j = 0; j < 4; ++j)
      bf[j] = *(const short8*)(Bs + (wc * 64 + j * 16 + lr) * 32 + lk * 8);
#pragma unroll
    for (int i = 0; i < 4; ++i)
#pragma unroll
      for (int j = 0; j < 4; ++j) {
        if (IT == 0)
          acc[i][j] = __builtin_amdgcn_mfma_f32_16x16x32_bf16(
              af[i], bf[j], acc[i][j], 0, 0, 0);
        else
          acc[i][j] = __builtin_amdgcn_mfma_f32_16x16x32_f16(
              __builtin_bit_cast(half8, af[i]), __builtin_bit_cast(half8, bf[j]),
              acc[i][j], 0, 0, 0);
      }
  }
#pragma unroll
  for (int i = 0; i < 4; ++i)
#pragma unroll
    for (int r = 0; r < 4; ++r) {
      int row = m0 + wr * 64 + i * 16 + lk * 4 + r;
#pragma unroll
      for (int j = 0; j < 4; ++j) {
        int col = n0 + wc * 64 + j * 16 + lr;
        float v = acc[i][j][r];
        if (OM == 0)
          ((float*)Cp)[(size_t)row * N + col] = v;
        else
          ((ushort*)Cp)[(size_t)col * M + row] = f2bf(v);
      }
    }
  if (OM == 3) {
#pragma unroll
    for (int i = 0; i < 4; ++i)
#pragma unroll
      for (int r = 0; r < 4; ++r) {
        float p = 0.f;
#pragma unroll
        for (int j = 0; j < 4; ++j) p += acc[i][j][r] * acc[i][j][r];
        p += __shfl_xor(p, 1); p += __shfl_xor(p, 2);
        p += __shfl_xor(p, 4); p += __shfl_xor(p, 8);
        if (lr == 0)
          atomicAdd(&snorm[m0 + wr * 64 + i * 16 + lk * 4 + r], p);
      }
  }
}

// ---------------------------------------------------------------------------
// Flash attention v3: no online rescale (scores bounded: |q.k/8| < ~5).
// O_unnorm = sum exp(s/8)*v ; per-lane lsum reduced once at end.
// exp folded: p = exp2(s * 0.125*log2(e)).
// ---------------------------------------------------------------------------
__global__ __launch_bounds__(256) void flash_mfma(
    const ushort* __restrict__ Qg, const ushort* __restrict__ Kg,
    const ushort* __restrict__ Vg, ushort* __restrict__ O, int T, int nqt)
{
  const int h = blockIdx.x;
  const int qt = nqt - 1 - blockIdx.y;  // heavy blocks first
  const int q0 = qt * 64;
  const int tid = threadIdx.x, w = tid >> 6, lane = tid & 63;
  const int lr = lane & 15, lk = lane >> 4;
  const ushort* Q = Qg + (size_t)h * T * 64;
  const ushort* K = Kg + (size_t)h * T * 64;
  const ushort* V = Vg + (size_t)h * 64 * T;
  __shared__ __align__(16) ushort Ps[4][16 * 72];
  const float CEXP = 0.18033688f;  // 0.125 * log2(e)

  short8 qa0 = *(const short8*)(Q + (size_t)(q0 + w * 16 + lr) * 64 + lk * 8);
  short8 qa1 = *(const short8*)(Q + (size_t)(q0 + w * 16 + lr) * 64 + 32 + lk * 8);
  f32x4 o[4] = {};
  float ls[4] = {0.f, 0.f, 0.f, 0.f};

  // preload K tile 0
  short8 kb0[4], kb1[4];
#pragma unroll
  for (int c = 0; c < 4; ++c) {
    const ushort* kp = K + (size_t)(c * 16 + lr) * 64 + lk * 8;
    kb0[c] = *(const short8*)kp;
    kb1[c] = *(const short8*)(kp + 32);
  }

  for (int kt = 0; kt <= qt; ++kt) {
    const int k0 = kt * 64;
    // V loads for current tile — issue early, consumed after softmax
    short8 vb0[4], vb1[4];
#pragma unroll
    for (int c = 0; c < 4; ++c) {
      const ushort* vp = V + (size_t)(c * 16 + lr) * T + k0 + lk * 8;
      vb0[c] = *(const short8*)vp;
      vb1[c] = *(const short8*)(vp + 32);
    }
    // S = Q K^T
    f32x4 s[4];
#pragma unroll
    for (int c = 0; c < 4; ++c) {
      f32x4 z = {};
      z = __builtin_amdgcn_mfma_f32_16x16x32_bf16(qa0, kb0[c], z, 0, 0, 0);
      z = __builtin_amdgcn_mfma_f32_16x16x32_bf16(qa1, kb1[c], z, 0, 0, 0);
      s[c] = z;
    }
    // prefetch next K tile (regs free after S mfma issue)
    if (kt < qt) {
#pragma unroll
      for (int c = 0; c < 4; ++c) {
        const ushort* kp = K + (size_t)(k0 + 64 + c * 16 + lr) * 64 + lk * 8;
        kb0[c] = *(const short8*)kp;
        kb1[c] = *(const short8*)(kp + 32);
      }
    }
    const bool diag = (kt == qt);
    const int rowbase = q0 + w * 16 + lk * 4;
#pragma unroll
    for (int c = 0; c < 4; ++c) {
      const int col = k0 + c * 16 + lr;
#pragma unroll
      for (int r = 0; r < 4; ++r) {
        float p = exp2f(s[c][r] * CEXP);
        if (diag && col > rowbase + r) p = 0.f;
        ls[r] += p;
        Ps[w][(lk * 4 + r) * 72 + c * 16 + lr] = f2bf(p);
      }
    }
    short8 pa0 = *(const short8*)(&Ps[w][lr * 72 + lk * 8]);
    short8 pa1 = *(const short8*)(&Ps[w][lr * 72 + 32 + lk * 8]);
#pragma unroll
    for (int c = 0; c < 4; ++c) {
      o[c] = __builtin_amdgcn_mfma_f32_16x16x32_bf16(pa0, vb0[c], o[c], 0, 0, 0);
      o[c] = __builtin_amdgcn_mfma_f32_16x16x32_bf16(pa1, vb1[c], o[c], 0, 0, 0);
    }
  }
  // one-time cross-lane reduction of lsum (over lr group; same lk = same rows)
#pragma unroll
  for (int r = 0; r < 4; ++r) {
    ls[r] += __shfl_xor(ls[r], 1);
    ls[r] += __shfl_xor(ls[r], 2);
    ls[r] += __shfl_xor(ls[r], 4);
    ls[r] += __shfl_xor(ls[r], 8);
  }
  ushort* Oh = O + (size_t)h * T * 64;
#pragma unroll
  for (int c = 0; c < 4; ++c)
#pragma unroll
    for (int r = 0; r < 4; ++r) {
      int row = q0 + w * 16 + lk * 4 + r;
      Oh[(size_t)row * 64 + c * 16 + lr] = f2bf(o[c][r] / ls[r]);
    }
}

// ---------------------------------------------------------------------------
// Branch 2: segmented r-score + softmax weights (as round 3)
// ---------------------------------------------------------------------------
__global__ __launch_bounds__(256) void rscore2(
    const float* __restrict__ x, const float* __restrict__ wr,
    float* __restrict__ rpart, int T, int E)
{
  const int h = blockIdx.y;
  const int e0 = blockIdx.z * 64;
  const int t0 = (blockIdx.x * 256 + threadIdx.x) * 4;
  const float* wrh = wr + (size_t)h * E * T;
  float4 acc = {0.f, 0.f, 0.f, 0.f};
  for (int e = e0; e < e0 + 64; ++e) {
    float4 w4 = *(const float4*)(wrh + (size_t)e * T + t0);
    acc.x += x[(size_t)(t0 + 0) * E + e] * w4.x;
    acc.y += x[(size_t)(t0 + 1) * E + e] * w4.y;
    acc.z += x[(size_t)(t0 + 2) * E + e] * w4.z;
    acc.w += x[(size_t)(t0 + 3) * E + e] * w4.w;
  }
  *(float4*)(rpart + ((size_t)blockIdx.z * HH + h) * T + t0) = acc;
}

__global__ __launch_bounds__(256) void rsoftmax2(
    const float* __restrict__ rpart, float* __restrict__ w, int T)
{
  const int h = blockIdx.x;
  __shared__ float rs[TT];
  __shared__ float red[4];
  for (int t = threadIdx.x; t < T; t += 256) {
    float a = 0.f;
#pragma unroll
    for (int s = 0; s < 16; ++s) a += rpart[((size_t)s * HH + h) * T + t];
    rs[t] = a;
  }
  __syncthreads();
  float mx = -1e30f;
  for (int t = threadIdx.x; t < T; t += 256) mx = fmaxf(mx, rs[t]);
#pragma unroll
  for (int o = 32; o; o >>= 1) mx = fmaxf(mx, __shfl_xor(mx, o));
  if ((threadIdx.x & 63) == 0) red[threadIdx.x >> 6] = mx;
  __syncthreads();
  mx = fmaxf(fmaxf(red[0], red[1]), fmaxf(red[2], red[3]));
  float* wh = w + (size_t)h * T;
  for (int t = threadIdx.x; t < T; t += 256)
    wh[t] = __expf((rs[t] - mx) * 0.125f);
}

// ---------------------------------------------------------------------------
// RRP prefix scan, two passes, grid (H,32) x 1 wave. seg = 64 k's.
// segsum layout: [(h*32+seg)*65] = num[0..63], [64] = den
// ---------------------------------------------------------------------------
__global__ __launch_bounds__(64) void rrp_part(
    const float* __restrict__ wgt, const ushort* __restrict__ rv,
    float* __restrict__ segsum, int T)
{
  const int h = blockIdx.x, seg = blockIdx.y, d = threadIdx.x;
  const int segLen = T >> 5;
  const float* wh = wgt + (size_t)h * T;
  const ushort* rvh = rv + (size_t)h * T * 64;
  const int kbeg = seg * segLen, kend = kbeg + segLen;
  float num = 0.f, den = 0.f;
  for (int k = kbeg; k < kend; ++k) {
    float wk = wh[k];
    num += wk * bf2f(rvh[(size_t)k * 64 + d]);
    den += wk;
  }
  float* o = segsum + ((size_t)h * 32 + seg) * 65;
  o[d] = num;
  if (d == 0) o[64] = den;
}

__global__ __launch_bounds__(64) void rrp_scan2(
    const float* __restrict__ wgt, const ushort* __restrict__ rv,
    const float* __restrict__ segsum, ushort* __restrict__ out, int T)
{
  const int h = blockIdx.x, seg = blockIdx.y, d = threadIdx.x;
  const int segLen = T >> 5;
  const float* wh = wgt + (size_t)h * T;
  const ushort* rvh = rv + (size_t)h * T * 64;
  ushort* oh = out + (size_t)h * T * 64;
  float num = 0.f, den = 0.f;
  for (int s = 0; s < seg; ++s) {
    const float* p = segsum + ((size_t)h * 32 + s) * 65;
    num += p[d];
    den += p[64];
  }
  const int kbeg = seg * segLen, kend = kbeg + segLen;
  for (int k = kbeg; k < kend; ++k) {
    float wk = wh[k];
    num += wk * bf2f(rvh[(size_t)k * 64 + d]);
    den += wk;
    oh[(size_t)k * 64 + d] = f2bf(num / den);
  }
}

// ---------------------------------------------------------------------------
// Branch 3: W[q][k] (bf16) + row denominators. s_t = snorm[t]/32.
// ---------------------------------------------------------------------------
__global__ __launch_bounds__(256) void janus_w(
    const float* __restrict__ snorm, ushort* __restrict__ Wb,
    float* __restrict__ den, int T)
{
  const int q = blockIdx.x;
  const float sq = snorm[q] * 0.03125f;
  float mx = -1e30f;
  for (int k = threadIdx.x; k <= q; k += 256)
    mx = fmaxf(mx, sq * (snorm[k] * 0.03125f));
#pragma unroll
  for (int o = 32; o; o >>= 1) mx = fmaxf(mx, __shfl_xor(mx, o));
  __shared__ float red[4];
  if ((threadIdx.x & 63) == 0) red[threadIdx.x >> 6] = mx;
  __syncthreads();
  mx = fmaxf(fmaxf(red[0], red[1]), fmaxf(red[2], red[3]));
  float sum = 0.f;
  ushort* Wq = Wb + (size_t)q * T;
  for (int k = threadIdx.x; k < T; k += 256) {
    float wv = (k <= q) ? __expf(sq * (snorm[k] * 0.03125f) - mx) : 0.f;
    ushort wb = f2bf(wv);
    Wq[k] = wb;
    sum += bf2f(wb);
  }
#pragma unroll
  for (int o = 32; o; o >>= 1) sum += __shfl_xor(sum, o);
  __syncthreads();
  if ((threadIdx.x & 63) == 0) red[threadIdx.x >> 6] = sum;
  __syncthreads();
  if (threadIdx.x == 0) den[q] = red[0] + red[1] + red[2] + red[3];
}

// ---------------------------------------------------------------------------
// Gated combine -> comb bf16 (T,E)
// ---------------------------------------------------------------------------
__global__ __launch_bounds__(256) void combine_kernel(
    const ushort* __restrict__ a1, const ushort* __restrict__ a2,
    const float* __restrict__ jraw, const float* __restrict__ denj,
    const float* __restrict__ gate, ushort* __restrict__ comb, int T)
{
  const int idx = blockIdx.x * 256 + threadIdx.x;
  const int t = idx >> 10;
  const int c = idx & 1023;
  const int h = c >> 6;
  const int d = c & 63;
  float g0 = gate[h * 3 + 0], g1 = gate[h * 3 + 1], g2 = gate[h * 3 + 2];
  float mg = fmaxf(g0, fmaxf(g1, g2));
  float e0 = __expf(g0 - mg), e1 = __expf(g1 - mg), e2 = __expf(g2 - mg);
  float inv = 1.f / (e0 + e1 + e2);
  const size_t hd = ((size_t)h * T + t) * 64 + d;
  float v = (e0 * bf2f(a1[hd]) + e1 * bf2f(a2[hd]) + e2 * jraw[idx] / denj[t]) * inv;
  comb[idx] = f2bf(v);
}

// ---------------------------------------------------------------------------
extern "C" void kernel_launch(void* const* d_in, const int* in_sizes, int n_in,
                              void* d_out, int out_size, void* d_ws, size_t ws_size,
                              hipStream_t stream)
{
  (void)in_sizes; (void)n_in; (void)out_size; (void)ws_size;
  const float* x    = (const float*)d_in[0];
  const float* wq   = (const float*)d_in[1];
  const float* wk   = (const float*)d_in[2];
  const float* wv   = (const float*)d_in[3];
  const float* wr   = (const float*)d_in[4];
  const float* wvr  = (const float*)d_in[5];
  const float* wj   = (const float*)d_in[6];
  const float* gate = (const float*)d_in[7];
  const float* wo   = (const float*)d_in[8];
  float* out = (float*)d_out;

  const int T = TT, E = EE, H = HH;
  const size_t TE = (size_t)T * E;
  const size_t EE2 = (size_t)E * E;
  const size_t TT2 = (size_t)T * T;

  ushort* u = (ushort*)d_ws;
  ushort* xbf   = u;
  ushort* xh    = xbf + TE;
  ushort* wqb   = xh + TE;
  ushort* wkb   = wqb + EE2;
  ushort* wvb   = wkb + EE2;
  ushort* wvrb  = wvb + EE2;
  ushort* wob   = wvrb + EE2;
  ushort* wjh   = wob + EE2;
  ushort* qhb   = wjh + EE2;      // (H,T,64) bf16
  ushort* khb   = qhb + TE;       // (H,T,64) bf16
  ushort* vtb   = khb + TE;       // (H,64,T) bf16
  ushort* rvhb  = vtb + TE;       // (H,T,64) bf16
  ushort* echoT = rvhb + TE;      // (E,T)    bf16
  ushort* a1b   = echoT + TE;     // (H,T,64) bf16
  ushort* a2b   = a1b + TE;       // (H,T,64) bf16
  ushort* Wbf   = a2b + TE;       // (T,T)    bf16
  ushort* combb = Wbf + TT2;      // (T,E)    bf16
  float* jraw   = (float*)(combb + TE);   // (T,E) fp32
  float* wwb    = jraw + TE;              // (H,T)
  float* snorm  = wwb + (size_t)H * T;    // (T)
  float* denj   = snorm + T;              // (T)
  float* rpart  = denj + T;               // (16,H,T)
  float* segsum = rpart + (size_t)16 * H * T;  // (H,32,65)

  dim3 blk(256);
  cvt_x_k<<<(int)(TE / 1024), blk, 0, stream>>>(x, xbf, xh, snorm, (int)TE);
  cvt_w_k<<<dim3((int)(EE2 / 1024), 6), blk, 0, stream>>>(
      wq, wk, wv, wvr, wo, wj, wqb, wkb, wvb, wvrb, wob, wjh, (int)EE2);

  // 4 bf16 projections in one dispatch
  proj4<<<dim3(E / 128, T / 128, 4), blk, 0, stream>>>(
      xbf, wqb, wkb, wvb, wvrb, qhb, khb, vtb, rvhb, T, E, E);
  // echo (fp16) -> echoT + row norms
  gemm_mfma<1, 3, false><<<dim3(E / 128, T / 128), blk, 0, stream>>>(
      xh, wjh, echoT, snorm, T, E, E);

  // branch 2 scores
  rscore2<<<dim3(T / 1024, H, 16), blk, 0, stream>>>(x, wr, rpart, T, E);
  rsoftmax2<<<H, blk, 0, stream>>>(rpart, wwb, T);

  // branch 1: flash
  flash_mfma<<<dim3(H, T / 64), blk, 0, stream>>>(qhb, khb, vtb, a1b, T, T / 64);

  // branch 2: prefix scan (2-pass, 512 blocks each)
  rrp_part<<<dim3(H, 32), dim3(64), 0, stream>>>(wwb, rvhb, segsum, T);
  rrp_scan2<<<dim3(H, 32), dim3(64), 0, stream>>>(wwb, rvhb, segsum, a2b, T);

  // branch 3: W + causal GEMM
  janus_w<<<T, blk, 0, stream>>>(snorm, Wbf, denj, T);
  gemm_mfma<0, 0, true><<<dim3(E / 128, T / 128), blk, 0, stream>>>(
      Wbf, echoT, jraw, nullptr, T, E, T);

  // combine + output projection
  combine_kernel<<<(int)(TE / 256), blk, 0, stream>>>(a1b, a2b, jraw, denj,
                                                      gate, combb, T);
  gemm_mfma<0, 0, false><<<dim3(E / 128, T / 128), blk, 0, stream>>>(
      combb, wob, out, nullptr, T, E, E);
}

// Round 5
// 528.087 us; speedup vs baseline: 5.2032x; 1.0818x over previous
//
#include <hip/hip_runtime.h>
#include <cstddef>

#define TT 2048
#define EE 1024
#define HH 16

typedef unsigned short ushort;
typedef unsigned int uint;
typedef __attribute__((ext_vector_type(8))) short short8;
typedef __attribute__((ext_vector_type(8))) _Float16 half8;
typedef __attribute__((ext_vector_type(4))) float f32x4;
typedef __attribute__((ext_vector_type(4))) ushort ushort4v;

__device__ __forceinline__ ushort f2bf(float f) {
  uint u = __builtin_bit_cast(uint, f);
  u = (u + 0x7FFFu + ((u >> 16) & 1u)) >> 16;
  return (ushort)u;
}
__device__ __forceinline__ float bf2f(ushort h) {
  return __builtin_bit_cast(float, (uint)h << 16);
}

// ---------------------------------------------------------------------------
// Conversions (fused). cvt_x also zeroes snorm (block 0).
// ---------------------------------------------------------------------------
__global__ __launch_bounds__(256) void cvt_x_k(
    const float* __restrict__ in, ushort* __restrict__ obf,
    ushort* __restrict__ oh, float* __restrict__ snorm, int n) {
  if (blockIdx.x == 0) {
    for (int i = threadIdx.x; i < TT; i += 256) snorm[i] = 0.f;
  }
  int i = (blockIdx.x * 256 + threadIdx.x) * 4;
  if (i >= n) return;
  float4 v = *(const float4*)(in + i);
  ushort4v b, h;
  b.x = f2bf(v.x); b.y = f2bf(v.y); b.z = f2bf(v.z); b.w = f2bf(v.w);
  h.x = __builtin_bit_cast(ushort, (_Float16)v.x);
  h.y = __builtin_bit_cast(ushort, (_Float16)v.y);
  h.z = __builtin_bit_cast(ushort, (_Float16)v.z);
  h.w = __builtin_bit_cast(ushort, (_Float16)v.w);
  *(ushort4v*)(obf + i) = b;
  *(ushort4v*)(oh + i) = h;
}

__global__ __launch_bounds__(256) void cvt_w_k(
    const float* __restrict__ s0, const float* __restrict__ s1,
    const float* __restrict__ s2, const float* __restrict__ s3,
    const float* __restrict__ s4, const float* __restrict__ s5,
    ushort* __restrict__ d0, ushort* __restrict__ d1,
    ushort* __restrict__ d2, ushort* __restrict__ d3,
    ushort* __restrict__ d4, ushort* __restrict__ d5, int n) {
  const int which = blockIdx.y;
  const float* src; ushort* dst;
  switch (which) {
    case 0: src = s0; dst = d0; break;
    case 1: src = s1; dst = d1; break;
    case 2: src = s2; dst = d2; break;
    case 3: src = s3; dst = d3; break;
    case 4: src = s4; dst = d4; break;
    default: src = s5; dst = d5; break;
  }
  int i = (blockIdx.x * 256 + threadIdx.x) * 4;
  if (i >= n) return;
  float4 v = *(const float4*)(src + i);
  ushort4v o;
  if (which == 5) {
    o.x = __builtin_bit_cast(ushort, (_Float16)v.x);
    o.y = __builtin_bit_cast(ushort, (_Float16)v.y);
    o.z = __builtin_bit_cast(ushort, (_Float16)v.z);
    o.w = __builtin_bit_cast(ushort, (_Float16)v.w);
  } else {
    o.x = f2bf(v.x); o.y = f2bf(v.y); o.z = f2bf(v.z); o.w = f2bf(v.w);
  }
  *(ushort4v*)(dst + i) = o;
}

// ---------------------------------------------------------------------------
// x (T,E) fp32 -> xT (E,T) fp32, 32x32 LDS tiles
// ---------------------------------------------------------------------------
__global__ __launch_bounds__(256) void transpose_k(
    const float* __restrict__ in, float* __restrict__ outT, int M, int N)
{
  __shared__ float tile[32][33];
  const int bn = blockIdx.x * 32;  // N (e) base
  const int bm = blockIdx.y * 32;  // M (t) base
  const int tx = threadIdx.x & 31, ty = threadIdx.x >> 5;  // 32 x 8
#pragma unroll
  for (int i = 0; i < 32; i += 8)
    tile[ty + i][tx] = in[(size_t)(bm + ty + i) * N + bn + tx];
  __syncthreads();
#pragma unroll
  for (int i = 0; i < 32; i += 8)
    outT[(size_t)(bn + ty + i) * M + bm + tx] = tile[tx][ty + i];
}

// ---------------------------------------------------------------------------
// Merged 5-way projection GEMM, z = blockIdx.z:
// z=0..3: bf16  x@W^T -> qhb/khb(OM1), vtb(OM2), rvhb(OM1)
// z=4:    f16   xh@wjh^T -> echoT (E,T bf16, OM3) + snorm row norms
// ---------------------------------------------------------------------------
__global__ __launch_bounds__(256) void proj5(
    const ushort* __restrict__ Abf, const ushort* __restrict__ Ah,
    const ushort* __restrict__ B0, const ushort* __restrict__ B1,
    const ushort* __restrict__ B2, const ushort* __restrict__ B3,
    const ushort* __restrict__ B4,
    ushort* __restrict__ C0, ushort* __restrict__ C1,
    ushort* __restrict__ C2, ushort* __restrict__ C3,
    ushort* __restrict__ C4, float* __restrict__ snorm,
    int M, int N, int K)
{
  const ushort* A; const ushort* B; ushort* C; int om;
  switch (blockIdx.z) {
    case 0: A = Abf; B = B0; C = C0; om = 1; break;
    case 1: A = Abf; B = B1; C = C1; om = 1; break;
    case 2: A = Abf; B = B2; C = C2; om = 2; break;
    case 3: A = Abf; B = B3; C = C3; om = 1; break;
    default: A = Ah; B = B4; C = C4; om = 3; break;
  }
  const bool f16 = (blockIdx.z == 4);
  __shared__ __align__(16) ushort As[128 * 32];
  __shared__ __align__(16) ushort Bs[128 * 32];
  const int tid = threadIdx.x;
  const int m0 = blockIdx.y * 128, n0 = blockIdx.x * 128;
  const int w = tid >> 6, lane = tid & 63;
  const int wr = w >> 1, wc = w & 1;
  const int lr = lane & 15, lk = lane >> 4;
  const int srow = tid >> 1, sk = (tid & 1) * 16;
  const ushort* Ag = A + (size_t)(m0 + srow) * K + sk;
  const ushort* Bg = B + (size_t)(n0 + srow) * K + sk;
  f32x4 acc[4][4] = {};
  for (int k0 = 0; k0 < K; k0 += 32) {
    short8 av0 = *(const short8*)(Ag + k0);
    short8 av1 = *(const short8*)(Ag + k0 + 8);
    short8 bv0 = *(const short8*)(Bg + k0);
    short8 bv1 = *(const short8*)(Bg + k0 + 8);
    __syncthreads();
    *(short8*)(As + srow * 32 + sk) = av0;
    *(short8*)(As + srow * 32 + sk + 8) = av1;
    *(short8*)(Bs + srow * 32 + sk) = bv0;
    *(short8*)(Bs + srow * 32 + sk + 8) = bv1;
    __syncthreads();
    short8 af[4], bf[4];
#pragma unroll
    for (int i = 0; i < 4; ++i)
      af[i] = *(const short8*)(As + (wr * 64 + i * 16 + lr) * 32 + lk * 8);
#pragma unroll
    for (int j = 0; j < 4; ++j)
      bf[j] = *(const short8*)(Bs + (wc * 64 + j * 16 + lr) * 32 + lk * 8);
    if (f16) {
#pragma unroll
      for (int i = 0; i < 4; ++i)
#pragma unroll
        for (int j = 0; j < 4; ++j)
          acc[i][j] = __builtin_amdgcn_mfma_f32_16x16x32_f16(
              __builtin_bit_cast(half8, af[i]), __builtin_bit_cast(half8, bf[j]),
              acc[i][j], 0, 0, 0);
    } else {
#pragma unroll
      for (int i = 0; i < 4; ++i)
#pragma unroll
        for (int j = 0; j < 4; ++j)
          acc[i][j] = __builtin_amdgcn_mfma_f32_16x16x32_bf16(
              af[i], bf[j], acc[i][j], 0, 0, 0);
    }
  }
#pragma unroll
  for (int i = 0; i < 4; ++i)
#pragma unroll
    for (int r = 0; r < 4; ++r) {
      int row = m0 + wr * 64 + i * 16 + lk * 4 + r;
#pragma unroll
      for (int j = 0; j < 4; ++j) {
        int col = n0 + wc * 64 + j * 16 + lr;
        ushort v = f2bf(acc[i][j][r]);
        if (om == 1)
          C[((size_t)(col >> 6) * M + row) * 64 + (col & 63)] = v;
        else if (om == 2)
          C[(size_t)(col >> 6) * 64 * M + (size_t)(col & 63) * M + row] = v;
        else
          C[(size_t)col * M + row] = v;
      }
    }
  if (om == 3) {
#pragma unroll
    for (int i = 0; i < 4; ++i)
#pragma unroll
      for (int r = 0; r < 4; ++r) {
        float p = 0.f;
#pragma unroll
        for (int j = 0; j < 4; ++j) p += acc[i][j][r] * acc[i][j][r];
        p += __shfl_xor(p, 1); p += __shfl_xor(p, 2);
        p += __shfl_xor(p, 4); p += __shfl_xor(p, 8);
        if (lr == 0)
          atomicAdd(&snorm[m0 + wr * 64 + i * 16 + lk * 4 + r], p);
      }
  }
}

// ---------------------------------------------------------------------------
// Generic MFMA GEMM (janus / out). bf16 only here.
// OM: 0 fp32 (M,N). CZ: causal A.
// ---------------------------------------------------------------------------
template<bool CZ>
__global__ __launch_bounds__(256) void gemm_mfma(
    const ushort* __restrict__ A, const ushort* __restrict__ B,
    float* __restrict__ Cp, int M, int N, int K)
{
  __shared__ __align__(16) ushort As[128 * 32];
  __shared__ __align__(16) ushort Bs[128 * 32];
  const int tid = threadIdx.x;
  const int m0 = blockIdx.y * 128, n0 = blockIdx.x * 128;
  const int w = tid >> 6, lane = tid & 63;
  const int wr = w >> 1, wc = w & 1;
  const int lr = lane & 15, lk = lane >> 4;
  const int srow = tid >> 1, sk = (tid & 1) * 16;
  const ushort* Ag = A + (size_t)(m0 + srow) * K + sk;
  const ushort* Bg = B + (size_t)(n0 + srow) * K + sk;
  f32x4 acc[4][4] = {};
  const int Keff = CZ ? (K < m0 + 128 ? K : m0 + 128) : K;
  for (int k0 = 0; k0 < Keff; k0 += 32) {
    short8 av0 = *(const short8*)(Ag + k0);
    short8 av1 = *(const short8*)(Ag + k0 + 8);
    short8 bv0 = *(const short8*)(Bg + k0);
    short8 bv1 = *(const short8*)(Bg + k0 + 8);
    __syncthreads();
    *(short8*)(As + srow * 32 + sk) = av0;
    *(short8*)(As + srow * 32 + sk + 8) = av1;
    *(short8*)(Bs + srow * 32 + sk) = bv0;
    *(short8*)(Bs + srow * 32 + sk + 8) = bv1;
    __syncthreads();
    short8 af[4], bf[4];
#pragma unroll
    for (int i = 0; i < 4; ++i)
      af[i] = *(const short8*)(As + (wr * 64 + i * 16 + lr) * 32 + lk * 8);
#pragma unroll
    for (int j = 0; j < 4; ++j)
      bf[j] = *(const short8*)(Bs + (wc * 64 + j * 16 + lr) * 32 + lk * 8);
#pragma unroll
    for (int i = 0; i < 4; ++i)
#pragma unroll
      for (int j = 0; j < 4; ++j)
        acc[i][j] = __builtin_amdgcn_mfma_f32_16x16x32_bf16(
            af[i], bf[j], acc[i][j], 0, 0, 0);
  }
#pragma unroll
  for (int i = 0; i < 4; ++i)
#pragma unroll
    for (int r = 0; r < 4; ++r) {
      int row = m0 + wr * 64 + i * 16 + lk * 4 + r;
#pragma unroll
      for (int j = 0; j < 4; ++j) {
        int col = n0 + wc * 64 + j * 16 + lr;
        Cp[(size_t)row * N + col] = acc[i][j][r];
      }
    }
}

// ---------------------------------------------------------------------------
// Flash attention v3 (round-4, unchanged): no online rescale.
// ---------------------------------------------------------------------------
__global__ __launch_bounds__(256) void flash_mfma(
    const ushort* __restrict__ Qg, const ushort* __restrict__ Kg,
    const ushort* __restrict__ Vg, ushort* __restrict__ O, int T, int nqt)
{
  const int h = blockIdx.x;
  const int qt = nqt - 1 - blockIdx.y;
  const int q0 = qt * 64;
  const int tid = threadIdx.x, w = tid >> 6, lane = tid & 63;
  const int lr = lane & 15, lk = lane >> 4;
  const ushort* Q = Qg + (size_t)h * T * 64;
  const ushort* K = Kg + (size_t)h * T * 64;
  const ushort* V = Vg + (size_t)h * 64 * T;
  __shared__ __align__(16) ushort Ps[4][16 * 72];
  const float CEXP = 0.18033688f;  // 0.125 * log2(e)

  short8 qa0 = *(const short8*)(Q + (size_t)(q0 + w * 16 + lr) * 64 + lk * 8);
  short8 qa1 = *(const short8*)(Q + (size_t)(q0 + w * 16 + lr) * 64 + 32 + lk * 8);
  f32x4 o[4] = {};
  float ls[4] = {0.f, 0.f, 0.f, 0.f};

  short8 kb0[4], kb1[4];
#pragma unroll
  for (int c = 0; c < 4; ++c) {
    const ushort* kp = K + (size_t)(c * 16 + lr) * 64 + lk * 8;
    kb0[c] = *(const short8*)kp;
    kb1[c] = *(const short8*)(kp + 32);
  }

  for (int kt = 0; kt <= qt; ++kt) {
    const int k0 = kt * 64;
    short8 vb0[4], vb1[4];
#pragma unroll
    for (int c = 0; c < 4; ++c) {
      const ushort* vp = V + (size_t)(c * 16 + lr) * T + k0 + lk * 8;
      vb0[c] = *(const short8*)vp;
      vb1[c] = *(const short8*)(vp + 32);
    }
    f32x4 s[4];
#pragma unroll
    for (int c = 0; c < 4; ++c) {
      f32x4 z = {};
      z = __builtin_amdgcn_mfma_f32_16x16x32_bf16(qa0, kb0[c], z, 0, 0, 0);
      z = __builtin_amdgcn_mfma_f32_16x16x32_bf16(qa1, kb1[c], z, 0, 0, 0);
      s[c] = z;
    }
    if (kt < qt) {
#pragma unroll
      for (int c = 0; c < 4; ++c) {
        const ushort* kp = K + (size_t)(k0 + 64 + c * 16 + lr) * 64 + lk * 8;
        kb0[c] = *(const short8*)kp;
        kb1[c] = *(const short8*)(kp + 32);
      }
    }
    const bool diag = (kt == qt);
    const int rowbase = q0 + w * 16 + lk * 4;
#pragma unroll
    for (int c = 0; c < 4; ++c) {
      const int col = k0 + c * 16 + lr;
#pragma unroll
      for (int r = 0; r < 4; ++r) {
        float p = exp2f(s[c][r] * CEXP);
        if (diag && col > rowbase + r) p = 0.f;
        ls[r] += p;
        Ps[w][(lk * 4 + r) * 72 + c * 16 + lr] = f2bf(p);
      }
    }
    short8 pa0 = *(const short8*)(&Ps[w][lr * 72 + lk * 8]);
    short8 pa1 = *(const short8*)(&Ps[w][lr * 72 + 32 + lk * 8]);
#pragma unroll
    for (int c = 0; c < 4; ++c) {
      o[c] = __builtin_amdgcn_mfma_f32_16x16x32_bf16(pa0, vb0[c], o[c], 0, 0, 0);
      o[c] = __builtin_amdgcn_mfma_f32_16x16x32_bf16(pa1, vb1[c], o[c], 0, 0, 0);
    }
  }
#pragma unroll
  for (int r = 0; r < 4; ++r) {
    ls[r] += __shfl_xor(ls[r], 1);
    ls[r] += __shfl_xor(ls[r], 2);
    ls[r] += __shfl_xor(ls[r], 4);
    ls[r] += __shfl_xor(ls[r], 8);
  }
  ushort* Oh = O + (size_t)h * T * 64;
#pragma unroll
  for (int c = 0; c < 4; ++c)
#pragma unroll
    for (int r = 0; r < 4; ++r) {
      int row = q0 + w * 16 + lk * 4 + r;
      Oh[(size_t)row * 64 + c * 16 + lr] = f2bf(o[c][r] / ls[r]);
    }
}

// ---------------------------------------------------------------------------
// Branch 2: r-score with both streams coalesced via xT. grid (T/1024, H, 16).
// ---------------------------------------------------------------------------
__global__ __launch_bounds__(256) void rscore3(
    const float* __restrict__ xT, const float* __restrict__ wr,
    float* __restrict__ rpart, int T, int E)
{
  const int h = blockIdx.y;
  const int e0 = blockIdx.z * 64;
  const int t0 = (blockIdx.x * 256 + threadIdx.x) * 4;
  const float* wrh = wr + (size_t)h * E * T;
  float4 acc = {0.f, 0.f, 0.f, 0.f};
#pragma unroll 4
  for (int e = e0; e < e0 + 64; ++e) {
    float4 xv = *(const float4*)(xT + (size_t)e * T + t0);
    float4 wv = *(const float4*)(wrh + (size_t)e * T + t0);
    acc.x += xv.x * wv.x;
    acc.y += xv.y * wv.y;
    acc.z += xv.z * wv.z;
    acc.w += xv.w * wv.w;
  }
  *(float4*)(rpart + ((size_t)blockIdx.z * HH + h) * T + t0) = acc;
}

__global__ __launch_bounds__(256) void rsoftmax2(
    const float* __restrict__ rpart, float* __restrict__ w, int T)
{
  const int h = blockIdx.x;
  __shared__ float rs[TT];
  __shared__ float red[4];
  for (int t = threadIdx.x; t < T; t += 256) {
    float a = 0.f;
#pragma unroll
    for (int s = 0; s < 16; ++s) a += rpart[((size_t)s * HH + h) * T + t];
    rs[t] = a;
  }
  __syncthreads();
  float mx = -1e30f;
  for (int t = threadIdx.x; t < T; t += 256) mx = fmaxf(mx, rs[t]);
#pragma unroll
  for (int o = 32; o; o >>= 1) mx = fmaxf(mx, __shfl_xor(mx, o));
  if ((threadIdx.x & 63) == 0) red[threadIdx.x >> 6] = mx;
  __syncthreads();
  mx = fmaxf(fmaxf(red[0], red[1]), fmaxf(red[2], red[3]));
  float* wh = w + (size_t)h * T;
  for (int t = threadIdx.x; t < T; t += 256)
    wh[t] = __expf((rs[t] - mx) * 0.125f);
}

// ---------------------------------------------------------------------------
// RRP prefix scan, two passes, grid (H,32) x 1 wave.
// ---------------------------------------------------------------------------
__global__ __launch_bounds__(64) void rrp_part(
    const float* __restrict__ wgt, const ushort* __restrict__ rv,
    float* __restrict__ segsum, int T)
{
  const int h = blockIdx.x, seg = blockIdx.y, d = threadIdx.x;
  const int segLen = T >> 5;
  const float* wh = wgt + (size_t)h * T;
  const ushort* rvh = rv + (size_t)h * T * 64;
  const int kbeg = seg * segLen, kend = kbeg + segLen;
  float num = 0.f, den = 0.f;
  for (int k = kbeg; k < kend; ++k) {
    float wk = wh[k];
    num += wk * bf2f(rvh[(size_t)k * 64 + d]);
    den += wk;
  }
  float* o = segsum + ((size_t)h * 32 + seg) * 65;
  o[d] = num;
  if (d == 0) o[64] = den;
}

__global__ __launch_bounds__(64) void rrp_scan2(
    const float* __restrict__ wgt, const ushort* __restrict__ rv,
    const float* __restrict__ segsum, ushort* __restrict__ out, int T)
{
  const int h = blockIdx.x, seg = blockIdx.y, d = threadIdx.x;
  const int segLen = T >> 5;
  const float* wh = wgt + (size_t)h * T;
  const ushort* rvh = rv + (size_t)h * T * 64;
  ushort* oh = out + (size_t)h * T * 64;
  float num = 0.f, den = 0.f;
  for (int s = 0; s < seg; ++s) {
    const float* p = segsum + ((size_t)h * 32 + s) * 65;
    num += p[d];
    den += p[64];
  }
  const int kbeg = seg * segLen, kend = kbeg + segLen;
  for (int k = kbeg; k < kend; ++k) {
    float wk = wh[k];
    num += wk * bf2f(rvh[(size_t)k * 64 + d]);
    den += wk;
    oh[(size_t)k * 64 + d] = f2bf(num / den);
  }
}

// ---------------------------------------------------------------------------
// Branch 3: W[q][k] (bf16) + row denominators.
// ---------------------------------------------------------------------------
__global__ __launch_bounds__(256) void janus_w(
    const float* __restrict__ snorm, ushort* __restrict__ Wb,
    float* __restrict__ den, int T)
{
  const int q = blockIdx.x;
  const float sq = snorm[q] * 0.03125f;
  float mx = -1e30f;
  for (int k = threadIdx.x; k <= q; k += 256)
    mx = fmaxf(mx, sq * (snorm[k] * 0.03125f));
#pragma unroll
  for (int o = 32; o; o >>= 1) mx = fmaxf(mx, __shfl_xor(mx, o));
  __shared__ float red[4];
  if ((threadIdx.x & 63) == 0) red[threadIdx.x >> 6] = mx;
  __syncthreads();
  mx = fmaxf(fmaxf(red[0], red[1]), fmaxf(red[2], red[3]));
  float sum = 0.f;
  ushort* Wq = Wb + (size_t)q * T;
  for (int k = threadIdx.x; k < T; k += 256) {
    float wv = (k <= q) ? __expf(sq * (snorm[k] * 0.03125f) - mx) : 0.f;
    ushort wb = f2bf(wv);
    Wq[k] = wb;
    sum += bf2f(wb);
  }
#pragma unroll
  for (int o = 32; o; o >>= 1) sum += __shfl_xor(sum, o);
  __syncthreads();
  if ((threadIdx.x & 63) == 0) red[threadIdx.x >> 6] = sum;
  __syncthreads();
  if (threadIdx.x == 0) den[q] = red[0] + red[1] + red[2] + red[3];
}

// ---------------------------------------------------------------------------
// Gated combine -> comb bf16 (T,E)
// ---------------------------------------------------------------------------
__global__ __launch_bounds__(256) void combine_kernel(
    const ushort* __restrict__ a1, const ushort* __restrict__ a2,
    const float* __restrict__ jraw, const float* __restrict__ denj,
    const float* __restrict__ gate, ushort* __restrict__ comb, int T)
{
  const int idx = blockIdx.x * 256 + threadIdx.x;
  const int t = idx >> 10;
  const int c = idx & 1023;
  const int h = c >> 6;
  const int d = c & 63;
  float g0 = gate[h * 3 + 0], g1 = gate[h * 3 + 1], g2 = gate[h * 3 + 2];
  float mg = fmaxf(g0, fmaxf(g1, g2));
  float e0 = __expf(g0 - mg), e1 = __expf(g1 - mg), e2 = __expf(g2 - mg);
  float inv = 1.f / (e0 + e1 + e2);
  const size_t hd = ((size_t)h * T + t) * 64 + d;
  float v = (e0 * bf2f(a1[hd]) + e1 * bf2f(a2[hd]) + e2 * jraw[idx] / denj[t]) * inv;
  comb[idx] = f2bf(v);
}

// ---------------------------------------------------------------------------
extern "C" void kernel_launch(void* const* d_in, const int* in_sizes, int n_in,
                              void* d_out, int out_size, void* d_ws, size_t ws_size,
                              hipStream_t stream)
{
  (void)in_sizes; (void)n_in; (void)out_size; (void)ws_size;
  const float* x    = (const float*)d_in[0];
  const float* wq   = (const float*)d_in[1];
  const float* wk   = (const float*)d_in[2];
  const float* wv   = (const float*)d_in[3];
  const float* wr   = (const float*)d_in[4];
  const float* wvr  = (const float*)d_in[5];
  const float* wj   = (const float*)d_in[6];
  const float* gate = (const float*)d_in[7];
  const float* wo   = (const float*)d_in[8];
  float* out = (float*)d_out;

  const int T = TT, E = EE, H = HH;
  const size_t TE = (size_t)T * E;
  const size_t EE2 = (size_t)E * E;
  const size_t TT2 = (size_t)T * T;

  ushort* u = (ushort*)d_ws;
  ushort* xbf   = u;
  ushort* xh    = xbf + TE;
  ushort* wqb   = xh + TE;
  ushort* wkb   = wqb + EE2;
  ushort* wvb   = wkb + EE2;
  ushort* wvrb  = wvb + EE2;
  ushort* wob   = wvrb + EE2;
  ushort* wjh   = wob + EE2;
  ushort* qhb   = wjh + EE2;      // (H,T,64) bf16
  ushort* khb   = qhb + TE;       // (H,T,64) bf16
  ushort* vtb   = khb + TE;       // (H,64,T) bf16
  ushort* rvhb  = vtb + TE;       // (H,T,64) bf16
  ushort* echoT = rvhb + TE;      // (E,T)    bf16
  ushort* a1b   = echoT + TE;     // (H,T,64) bf16
  ushort* a2b   = a1b + TE;       // (H,T,64) bf16
  ushort* Wbf   = a2b + TE;       // (T,T)    bf16
  ushort* combb = Wbf + TT2;      // (T,E)    bf16
  float* jraw   = (float*)(combb + TE);   // (T,E) fp32
  float* wwb    = jraw + TE;              // (H,T)
  float* snorm  = wwb + (size_t)H * T;    // (T)
  float* denj   = snorm + T;              // (T)
  float* rpart  = denj + T;               // (16,H,T)
  float* segsum = rpart + (size_t)16 * H * T;   // (H,32,65)
  float* xT     = segsum + (size_t)H * 32 * 65; // (E,T) fp32

  dim3 blk(256);
  cvt_x_k<<<(int)(TE / 1024), blk, 0, stream>>>(x, xbf, xh, snorm, (int)TE);
  cvt_w_k<<<dim3((int)(EE2 / 1024), 6), blk, 0, stream>>>(
      wq, wk, wv, wvr, wo, wj, wqb, wkb, wvb, wvrb, wob, wjh, (int)EE2);
  transpose_k<<<dim3(E / 32, T / 32), blk, 0, stream>>>(x, xT, T, E);

  // 4 bf16 projections + echo(f16) in one dispatch
  proj5<<<dim3(E / 128, T / 128, 5), blk, 0, stream>>>(
      xbf, xh, wqb, wkb, wvb, wvrb, wjh,
      qhb, khb, vtb, rvhb, echoT, snorm, T, E, E);

  // branch 2 scores (both streams coalesced)
  rscore3<<<dim3(T / 1024, H, 16), blk, 0, stream>>>(xT, wr, rpart, T, E);
  rsoftmax2<<<H, blk, 0, stream>>>(rpart, wwb, T);

  // branch 1: flash
  flash_mfma<<<dim3(H, T / 64), blk, 0, stream>>>(qhb, khb, vtb, a1b, T, T / 64);

  // branch 2: prefix scan
  rrp_part<<<dim3(H, 32), dim3(64), 0, stream>>>(wwb, rvhb, segsum, T);
  rrp_scan2<<<dim3(H, 32), dim3(64), 0, stream>>>(wwb, rvhb, segsum, a2b, T);

  // branch 3: W + causal GEMM
  janus_w<<<T, blk, 0, stream>>>(snorm, Wbf, denj, T);
  gemm_mfma<true><<<dim3(E / 128, T / 128), blk, 0, stream>>>(
      Wbf, echoT, jraw, T, E, T);

  // combine + output projection
  combine_kernel<<<(int)(TE / 256), blk, 0, stream>>>(a1b, a2b, jraw, denj,
                                                      gate, combb, T);
  gemm_mfma<false><<<dim3(E / 128, T / 128), blk, 0, stream>>>(
      combb, wob, (float*)out, T, E, E);
}

// Round 6
// 521.265 us; speedup vs baseline: 5.2713x; 1.0131x over previous
//
#include <hip/hip_runtime.h>
#include <cstddef>

#define TT 2048
#define EE 1024
#define HH 16

typedef unsigned short ushort;
typedef unsigned int uint;
typedef __attribute__((ext_vector_type(8))) short short8;
typedef __attribute__((ext_vector_type(8))) _Float16 half8;
typedef __attribute__((ext_vector_type(4))) float f32x4;
typedef __attribute__((ext_vector_type(4))) ushort ushort4v;

__device__ __forceinline__ ushort f2bf(float f) {
  uint u = __builtin_bit_cast(uint, f);
  u = (u + 0x7FFFu + ((u >> 16) & 1u)) >> 16;
  return (ushort)u;
}
__device__ __forceinline__ float bf2f(ushort h) {
  return __builtin_bit_cast(float, (uint)h << 16);
}

// ---------------------------------------------------------------------------
// Conversions (fused). cvt_x also zeroes snorm (block 0).
// ---------------------------------------------------------------------------
__global__ __launch_bounds__(256) void cvt_x_k(
    const float* __restrict__ in, ushort* __restrict__ obf,
    ushort* __restrict__ oh, float* __restrict__ snorm, int n) {
  if (blockIdx.x == 0) {
    for (int i = threadIdx.x; i < TT; i += 256) snorm[i] = 0.f;
  }
  int i = (blockIdx.x * 256 + threadIdx.x) * 4;
  if (i >= n) return;
  float4 v = *(const float4*)(in + i);
  ushort4v b, h;
  b.x = f2bf(v.x); b.y = f2bf(v.y); b.z = f2bf(v.z); b.w = f2bf(v.w);
  h.x = __builtin_bit_cast(ushort, (_Float16)v.x);
  h.y = __builtin_bit_cast(ushort, (_Float16)v.y);
  h.z = __builtin_bit_cast(ushort, (_Float16)v.z);
  h.w = __builtin_bit_cast(ushort, (_Float16)v.w);
  *(ushort4v*)(obf + i) = b;
  *(ushort4v*)(oh + i) = h;
}

__global__ __launch_bounds__(256) void cvt_w_k(
    const float* __restrict__ s0, const float* __restrict__ s1,
    const float* __restrict__ s2, const float* __restrict__ s3,
    const float* __restrict__ s4, const float* __restrict__ s5,
    ushort* __restrict__ d0, ushort* __restrict__ d1,
    ushort* __restrict__ d2, ushort* __restrict__ d3,
    ushort* __restrict__ d4, ushort* __restrict__ d5, int n) {
  const int which = blockIdx.y;
  const float* src; ushort* dst;
  switch (which) {
    case 0: src = s0; dst = d0; break;
    case 1: src = s1; dst = d1; break;
    case 2: src = s2; dst = d2; break;
    case 3: src = s3; dst = d3; break;
    case 4: src = s4; dst = d4; break;
    default: src = s5; dst = d5; break;
  }
  int i = (blockIdx.x * 256 + threadIdx.x) * 4;
  if (i >= n) return;
  float4 v = *(const float4*)(src + i);
  ushort4v o;
  if (which == 5) {
    o.x = __builtin_bit_cast(ushort, (_Float16)v.x);
    o.y = __builtin_bit_cast(ushort, (_Float16)v.y);
    o.z = __builtin_bit_cast(ushort, (_Float16)v.z);
    o.w = __builtin_bit_cast(ushort, (_Float16)v.w);
  } else {
    o.x = f2bf(v.x); o.y = f2bf(v.y); o.z = f2bf(v.z); o.w = f2bf(v.w);
  }
  *(ushort4v*)(dst + i) = o;
}

// ---------------------------------------------------------------------------
// x (T,E) fp32 -> xT (E,T) fp32, 32x32 LDS tiles
// ---------------------------------------------------------------------------
__global__ __launch_bounds__(256) void transpose_k(
    const float* __restrict__ in, float* __restrict__ outT, int M, int N)
{
  __shared__ float tile[32][33];
  const int bn = blockIdx.x * 32;
  const int bm = blockIdx.y * 32;
  const int tx = threadIdx.x & 31, ty = threadIdx.x >> 5;
#pragma unroll
  for (int i = 0; i < 32; i += 8)
    tile[ty + i][tx] = in[(size_t)(bm + ty + i) * N + bn + tx];
  __syncthreads();
#pragma unroll
  for (int i = 0; i < 32; i += 8)
    outT[(size_t)(bn + ty + i) * M + bm + tx] = tile[tx][ty + i];
}

// ---------------------------------------------------------------------------
// Merged 5-way projection GEMM, z = blockIdx.z (round-5, unchanged)
// ---------------------------------------------------------------------------
__global__ __launch_bounds__(256) void proj5(
    const ushort* __restrict__ Abf, const ushort* __restrict__ Ah,
    const ushort* __restrict__ B0, const ushort* __restrict__ B1,
    const ushort* __restrict__ B2, const ushort* __restrict__ B3,
    const ushort* __restrict__ B4,
    ushort* __restrict__ C0, ushort* __restrict__ C1,
    ushort* __restrict__ C2, ushort* __restrict__ C3,
    ushort* __restrict__ C4, float* __restrict__ snorm,
    int M, int N, int K)
{
  const ushort* A; const ushort* B; ushort* C; int om;
  switch (blockIdx.z) {
    case 0: A = Abf; B = B0; C = C0; om = 1; break;
    case 1: A = Abf; B = B1; C = C1; om = 1; break;
    case 2: A = Abf; B = B2; C = C2; om = 2; break;
    case 3: A = Abf; B = B3; C = C3; om = 1; break;
    default: A = Ah; B = B4; C = C4; om = 3; break;
  }
  const bool f16 = (blockIdx.z == 4);
  __shared__ __align__(16) ushort As[128 * 32];
  __shared__ __align__(16) ushort Bs[128 * 32];
  const int tid = threadIdx.x;
  const int m0 = blockIdx.y * 128, n0 = blockIdx.x * 128;
  const int w = tid >> 6, lane = tid & 63;
  const int wr = w >> 1, wc = w & 1;
  const int lr = lane & 15, lk = lane >> 4;
  const int srow = tid >> 1, sk = (tid & 1) * 16;
  const ushort* Ag = A + (size_t)(m0 + srow) * K + sk;
  const ushort* Bg = B + (size_t)(n0 + srow) * K + sk;
  f32x4 acc[4][4] = {};
  for (int k0 = 0; k0 < K; k0 += 32) {
    short8 av0 = *(const short8*)(Ag + k0);
    short8 av1 = *(const short8*)(Ag + k0 + 8);
    short8 bv0 = *(const short8*)(Bg + k0);
    short8 bv1 = *(const short8*)(Bg + k0 + 8);
    __syncthreads();
    *(short8*)(As + srow * 32 + sk) = av0;
    *(short8*)(As + srow * 32 + sk + 8) = av1;
    *(short8*)(Bs + srow * 32 + sk) = bv0;
    *(short8*)(Bs + srow * 32 + sk + 8) = bv1;
    __syncthreads();
    short8 af[4], bf[4];
#pragma unroll
    for (int i = 0; i < 4; ++i)
      af[i] = *(const short8*)(As + (wr * 64 + i * 16 + lr) * 32 + lk * 8);
#pragma unroll
    for (int j = 0; j < 4; ++j)
      bf[j] = *(const short8*)(Bs + (wc * 64 + j * 16 + lr) * 32 + lk * 8);
    if (f16) {
#pragma unroll
      for (int i = 0; i < 4; ++i)
#pragma unroll
        for (int j = 0; j < 4; ++j)
          acc[i][j] = __builtin_amdgcn_mfma_f32_16x16x32_f16(
              __builtin_bit_cast(half8, af[i]), __builtin_bit_cast(half8, bf[j]),
              acc[i][j], 0, 0, 0);
    } else {
#pragma unroll
      for (int i = 0; i < 4; ++i)
#pragma unroll
        for (int j = 0; j < 4; ++j)
          acc[i][j] = __builtin_amdgcn_mfma_f32_16x16x32_bf16(
              af[i], bf[j], acc[i][j], 0, 0, 0);
    }
  }
#pragma unroll
  for (int i = 0; i < 4; ++i)
#pragma unroll
    for (int r = 0; r < 4; ++r) {
      int row = m0 + wr * 64 + i * 16 + lk * 4 + r;
#pragma unroll
      for (int j = 0; j < 4; ++j) {
        int col = n0 + wc * 64 + j * 16 + lr;
        ushort v = f2bf(acc[i][j][r]);
        if (om == 1)
          C[((size_t)(col >> 6) * M + row) * 64 + (col & 63)] = v;
        else if (om == 2)
          C[(size_t)(col >> 6) * 64 * M + (size_t)(col & 63) * M + row] = v;
        else
          C[(size_t)col * M + row] = v;
      }
    }
  if (om == 3) {
#pragma unroll
    for (int i = 0; i < 4; ++i)
#pragma unroll
      for (int r = 0; r < 4; ++r) {
        float p = 0.f;
#pragma unroll
        for (int j = 0; j < 4; ++j) p += acc[i][j][r] * acc[i][j][r];
        p += __shfl_xor(p, 1); p += __shfl_xor(p, 2);
        p += __shfl_xor(p, 4); p += __shfl_xor(p, 8);
        if (lr == 0)
          atomicAdd(&snorm[m0 + wr * 64 + i * 16 + lk * 4 + r], p);
      }
  }
}

// ---------------------------------------------------------------------------
// Generic MFMA GEMM (janus / out), fp32 out. CZ: causal A.
// ---------------------------------------------------------------------------
template<bool CZ>
__global__ __launch_bounds__(256) void gemm_mfma(
    const ushort* __restrict__ A, const ushort* __restrict__ B,
    float* __restrict__ Cp, int M, int N, int K)
{
  __shared__ __align__(16) ushort As[128 * 32];
  __shared__ __align__(16) ushort Bs[128 * 32];
  const int tid = threadIdx.x;
  const int m0 = blockIdx.y * 128, n0 = blockIdx.x * 128;
  const int w = tid >> 6, lane = tid & 63;
  const int wr = w >> 1, wc = w & 1;
  const int lr = lane & 15, lk = lane >> 4;
  const int srow = tid >> 1, sk = (tid & 1) * 16;
  const ushort* Ag = A + (size_t)(m0 + srow) * K + sk;
  const ushort* Bg = B + (size_t)(n0 + srow) * K + sk;
  f32x4 acc[4][4] = {};
  const int Keff = CZ ? (K < m0 + 128 ? K : m0 + 128) : K;
  for (int k0 = 0; k0 < Keff; k0 += 32) {
    short8 av0 = *(const short8*)(Ag + k0);
    short8 av1 = *(const short8*)(Ag + k0 + 8);
    short8 bv0 = *(const short8*)(Bg + k0);
    short8 bv1 = *(const short8*)(Bg + k0 + 8);
    __syncthreads();
    *(short8*)(As + srow * 32 + sk) = av0;
    *(short8*)(As + srow * 32 + sk + 8) = av1;
    *(short8*)(Bs + srow * 32 + sk) = bv0;
    *(short8*)(Bs + srow * 32 + sk + 8) = bv1;
    __syncthreads();
    short8 af[4], bf[4];
#pragma unroll
    for (int i = 0; i < 4; ++i)
      af[i] = *(const short8*)(As + (wr * 64 + i * 16 + lr) * 32 + lk * 8);
#pragma unroll
    for (int j = 0; j < 4; ++j)
      bf[j] = *(const short8*)(Bs + (wc * 64 + j * 16 + lr) * 32 + lk * 8);
#pragma unroll
    for (int i = 0; i < 4; ++i)
#pragma unroll
      for (int j = 0; j < 4; ++j)
        acc[i][j] = __builtin_amdgcn_mfma_f32_16x16x32_bf16(
            af[i], bf[j], acc[i][j], 0, 0, 0);
  }
#pragma unroll
  for (int i = 0; i < 4; ++i)
#pragma unroll
    for (int r = 0; r < 4; ++r) {
      int row = m0 + wr * 64 + i * 16 + lk * 4 + r;
#pragma unroll
      for (int j = 0; j < 4; ++j) {
        int col = n0 + wc * 64 + j * 16 + lr;
        Cp[(size_t)row * N + col] = acc[i][j][r];
      }
    }
}

// ---------------------------------------------------------------------------
// Flash attention v4: split-K. Block (h, qt, sp) covers k-tiles
// [sp*span, min(nk, (sp+1)*span)), span = ceil(nk/2). Emits unnormalized
// fp32 partials: pb[0..4095] = o (64x64), pb[4096..4159] = ls (64 rows).
// Valid because p = exp(s/8) needs no max subtraction (|s| < ~5).
// ---------------------------------------------------------------------------
__global__ __launch_bounds__(256) void flash_mfma(
    const ushort* __restrict__ Qg, const ushort* __restrict__ Kg,
    const ushort* __restrict__ Vg, float* __restrict__ pbuf, int T, int nqt)
{
  const int h = blockIdx.x;
  const int qt = nqt - 1 - blockIdx.y;  // heavy blocks first
  const int sp = blockIdx.z;
  const int q0 = qt * 64;
  const int nk = qt + 1;
  const int span = (nk + 1) >> 1;
  const int kb = sp * span;
  const int ke = (nk < kb + span) ? nk : (kb + span);
  const int tid = threadIdx.x, w = tid >> 6, lane = tid & 63;
  const int lr = lane & 15, lk = lane >> 4;
  const ushort* Q = Qg + (size_t)h * T * 64;
  const ushort* K = Kg + (size_t)h * T * 64;
  const ushort* V = Vg + (size_t)h * 64 * T;
  __shared__ __align__(16) ushort Ps[4][16 * 72];
  const float CEXP = 0.18033688f;  // 0.125 * log2(e)

  f32x4 o[4] = {};
  float ls[4] = {0.f, 0.f, 0.f, 0.f};

  if (kb < ke) {
    short8 qa0 = *(const short8*)(Q + (size_t)(q0 + w * 16 + lr) * 64 + lk * 8);
    short8 qa1 = *(const short8*)(Q + (size_t)(q0 + w * 16 + lr) * 64 + 32 + lk * 8);
    // preload K tile kb
    short8 kb0[4], kb1[4];
#pragma unroll
    for (int c = 0; c < 4; ++c) {
      const ushort* kp = K + (size_t)(kb * 64 + c * 16 + lr) * 64 + lk * 8;
      kb0[c] = *(const short8*)kp;
      kb1[c] = *(const short8*)(kp + 32);
    }
    for (int kt = kb; kt < ke; ++kt) {
      const int k0 = kt * 64;
      short8 vb0[4], vb1[4];
#pragma unroll
      for (int c = 0; c < 4; ++c) {
        const ushort* vp = V + (size_t)(c * 16 + lr) * T + k0 + lk * 8;
        vb0[c] = *(const short8*)vp;
        vb1[c] = *(const short8*)(vp + 32);
      }
      f32x4 s[4];
#pragma unroll
      for (int c = 0; c < 4; ++c) {
        f32x4 z = {};
        z = __builtin_amdgcn_mfma_f32_16x16x32_bf16(qa0, kb0[c], z, 0, 0, 0);
        z = __builtin_amdgcn_mfma_f32_16x16x32_bf16(qa1, kb1[c], z, 0, 0, 0);
        s[c] = z;
      }
      if (kt + 1 < ke) {
#pragma unroll
        for (int c = 0; c < 4; ++c) {
          const ushort* kp = K + (size_t)(k0 + 64 + c * 16 + lr) * 64 + lk * 8;
          kb0[c] = *(const short8*)kp;
          kb1[c] = *(const short8*)(kp + 32);
        }
      }
      const bool diag = (kt == qt);
      const int rowbase = q0 + w * 16 + lk * 4;
#pragma unroll
      for (int c = 0; c < 4; ++c) {
        const int col = k0 + c * 16 + lr;
#pragma unroll
        for (int r = 0; r < 4; ++r) {
          float p = exp2f(s[c][r] * CEXP);
          if (diag && col > rowbase + r) p = 0.f;
          ls[r] += p;
          Ps[w][(lk * 4 + r) * 72 + c * 16 + lr] = f2bf(p);
        }
      }
      short8 pa0 = *(const short8*)(&Ps[w][lr * 72 + lk * 8]);
      short8 pa1 = *(const short8*)(&Ps[w][lr * 72 + 32 + lk * 8]);
#pragma unroll
      for (int c = 0; c < 4; ++c) {
        o[c] = __builtin_amdgcn_mfma_f32_16x16x32_bf16(pa0, vb0[c], o[c], 0, 0, 0);
        o[c] = __builtin_amdgcn_mfma_f32_16x16x32_bf16(pa1, vb1[c], o[c], 0, 0, 0);
      }
    }
    // reduce ls across the lr-group (lanes sharing the same rows)
#pragma unroll
    for (int r = 0; r < 4; ++r) {
      ls[r] += __shfl_xor(ls[r], 1);
      ls[r] += __shfl_xor(ls[r], 2);
      ls[r] += __shfl_xor(ls[r], 4);
      ls[r] += __shfl_xor(ls[r], 8);
    }
  }
  float* pb = pbuf + ((size_t)(h * nqt + qt) * 2 + sp) * 4160;
#pragma unroll
  for (int c = 0; c < 4; ++c)
#pragma unroll
    for (int r = 0; r < 4; ++r) {
      int row = w * 16 + lk * 4 + r;
      pb[(size_t)row * 64 + c * 16 + lr] = o[c][r];
    }
  if (lr == 0) {
#pragma unroll
    for (int r = 0; r < 4; ++r)
      pb[4096 + w * 16 + lk * 4 + r] = ls[r];
  }
}

// merge split partials: O = (o0+o1)/(ls0+ls1), bf16 (H,T,64)
__global__ __launch_bounds__(256) void flash_merge(
    const float* __restrict__ pbuf, ushort* __restrict__ O, int T, int nqt)
{
  const int b = blockIdx.x;            // h*nqt + qt
  const int h = b / nqt, qt = b - h * nqt;
  const float* p0 = pbuf + (size_t)b * 2 * 4160;
  const float* p1 = p0 + 4160;
  ushort* Oh = O + ((size_t)h * T + qt * 64) * 64;
  __shared__ float lsum[64];
  if (threadIdx.x < 64)
    lsum[threadIdx.x] = p0[4096 + threadIdx.x] + p1[4096 + threadIdx.x];
  __syncthreads();
  for (int i = threadIdx.x; i < 4096; i += 256) {
    int r = i >> 6;
    Oh[i] = f2bf((p0[i] + p1[i]) / lsum[r]);
  }
}

// ---------------------------------------------------------------------------
// Branch 2: r-score (both streams coalesced via xT), round-5 unchanged
// ---------------------------------------------------------------------------
__global__ __launch_bounds__(256) void rscore3(
    const float* __restrict__ xT, const float* __restrict__ wr,
    float* __restrict__ rpart, int T, int E)
{
  const int h = blockIdx.y;
  const int e0 = blockIdx.z * 64;
  const int t0 = (blockIdx.x * 256 + threadIdx.x) * 4;
  const float* wrh = wr + (size_t)h * E * T;
  float4 acc = {0.f, 0.f, 0.f, 0.f};
#pragma unroll 4
  for (int e = e0; e < e0 + 64; ++e) {
    float4 xv = *(const float4*)(xT + (size_t)e * T + t0);
    float4 wv = *(const float4*)(wrh + (size_t)e * T + t0);
    acc.x += xv.x * wv.x;
    acc.y += xv.y * wv.y;
    acc.z += xv.z * wv.z;
    acc.w += xv.w * wv.w;
  }
  *(float4*)(rpart + ((size_t)blockIdx.z * HH + h) * T + t0) = acc;
}

__global__ __launch_bounds__(256) void rsoftmax2(
    const float* __restrict__ rpart, float* __restrict__ w, int T)
{
  const int h = blockIdx.x;
  __shared__ float rs[TT];
  __shared__ float red[4];
  for (int t = threadIdx.x; t < T; t += 256) {
    float a = 0.f;
#pragma unroll
    for (int s = 0; s < 16; ++s) a += rpart[((size_t)s * HH + h) * T + t];
    rs[t] = a;
  }
  __syncthreads();
  float mx = -1e30f;
  for (int t = threadIdx.x; t < T; t += 256) mx = fmaxf(mx, rs[t]);
#pragma unroll
  for (int o = 32; o; o >>= 1) mx = fmaxf(mx, __shfl_xor(mx, o));
  if ((threadIdx.x & 63) == 0) red[threadIdx.x >> 6] = mx;
  __syncthreads();
  mx = fmaxf(fmaxf(red[0], red[1]), fmaxf(red[2], red[3]));
  float* wh = w + (size_t)h * T;
  for (int t = threadIdx.x; t < T; t += 256)
    wh[t] = __expf((rs[t] - mx) * 0.125f);
}

// ---------------------------------------------------------------------------
// RRP prefix scan, two passes, grid (H,32) x 1 wave.
// ---------------------------------------------------------------------------
__global__ __launch_bounds__(64) void rrp_part(
    const float* __restrict__ wgt, const ushort* __restrict__ rv,
    float* __restrict__ segsum, int T)
{
  const int h = blockIdx.x, seg = blockIdx.y, d = threadIdx.x;
  const int segLen = T >> 5;
  const float* wh = wgt + (size_t)h * T;
  const ushort* rvh = rv + (size_t)h * T * 64;
  const int kbeg = seg * segLen, kend = kbeg + segLen;
  float num = 0.f, den = 0.f;
  for (int k = kbeg; k < kend; ++k) {
    float wk = wh[k];
    num += wk * bf2f(rvh[(size_t)k * 64 + d]);
    den += wk;
  }
  float* o = segsum + ((size_t)h * 32 + seg) * 65;
  o[d] = num;
  if (d == 0) o[64] = den;
}

__global__ __launch_bounds__(64) void rrp_scan2(
    const float* __restrict__ wgt, const ushort* __restrict__ rv,
    const float* __restrict__ segsum, ushort* __restrict__ out, int T)
{
  const int h = blockIdx.x, seg = blockIdx.y, d = threadIdx.x;
  const int segLen = T >> 5;
  const float* wh = wgt + (size_t)h * T;
  const ushort* rvh = rv + (size_t)h * T * 64;
  ushort* oh = out + (size_t)h * T * 64;
  float num = 0.f, den = 0.f;
  for (int s = 0; s < seg; ++s) {
    const float* p = segsum + ((size_t)h * 32 + s) * 65;
    num += p[d];
    den += p[64];
  }
  const int kbeg = seg * segLen, kend = kbeg + segLen;
  for (int k = kbeg; k < kend; ++k) {
    float wk = wh[k];
    num += wk * bf2f(rvh[(size_t)k * 64 + d]);
    den += wk;
    oh[(size_t)k * 64 + d] = f2bf(num / den);
  }
}

// ---------------------------------------------------------------------------
// Branch 3: W[q][k] (bf16) + row denominators.
// ---------------------------------------------------------------------------
__global__ __launch_bounds__(256) void janus_w(
    const float* __restrict__ snorm, ushort* __restrict__ Wb,
    float* __restrict__ den, int T)
{
  const int q = blockIdx.x;
  const float sq = snorm[q] * 0.03125f;
  float mx = -1e30f;
  for (int k = threadIdx.x; k <= q; k += 256)
    mx = fmaxf(mx, sq * (snorm[k] * 0.03125f));
#pragma unroll
  for (int o = 32; o; o >>= 1) mx = fmaxf(mx, __shfl_xor(mx, o));
  __shared__ float red[4];
  if ((threadIdx.x & 63) == 0) red[threadIdx.x >> 6] = mx;
  __syncthreads();
  mx = fmaxf(fmaxf(red[0], red[1]), fmaxf(red[2], red[3]));
  float sum = 0.f;
  ushort* Wq = Wb + (size_t)q * T;
  for (int k = threadIdx.x; k < T; k += 256) {
    float wv = (k <= q) ? __expf(sq * (snorm[k] * 0.03125f) - mx) : 0.f;
    ushort wb = f2bf(wv);
    Wq[k] = wb;
    sum += bf2f(wb);
  }
#pragma unroll
  for (int o = 32; o; o >>= 1) sum += __shfl_xor(sum, o);
  __syncthreads();
  if ((threadIdx.x & 63) == 0) red[threadIdx.x >> 6] = sum;
  __syncthreads();
  if (threadIdx.x == 0) den[q] = red[0] + red[1] + red[2] + red[3];
}

// ---------------------------------------------------------------------------
// Gated combine -> comb bf16 (T,E)
// ---------------------------------------------------------------------------
__global__ __launch_bounds__(256) void combine_kernel(
    const ushort* __restrict__ a1, const ushort* __restrict__ a2,
    const float* __restrict__ jraw, const float* __restrict__ denj,
    const float* __restrict__ gate, ushort* __restrict__ comb, int T)
{
  const int idx = blockIdx.x * 256 + threadIdx.x;
  const int t = idx >> 10;
  const int c = idx & 1023;
  const int h = c >> 6;
  const int d = c & 63;
  float g0 = gate[h * 3 + 0], g1 = gate[h * 3 + 1], g2 = gate[h * 3 + 2];
  float mg = fmaxf(g0, fmaxf(g1, g2));
  float e0 = __expf(g0 - mg), e1 = __expf(g1 - mg), e2 = __expf(g2 - mg);
  float inv = 1.f / (e0 + e1 + e2);
  const size_t hd = ((size_t)h * T + t) * 64 + d;
  float v = (e0 * bf2f(a1[hd]) + e1 * bf2f(a2[hd]) + e2 * jraw[idx] / denj[t]) * inv;
  comb[idx] = f2bf(v);
}

// ---------------------------------------------------------------------------
extern "C" void kernel_launch(void* const* d_in, const int* in_sizes, int n_in,
                              void* d_out, int out_size, void* d_ws, size_t ws_size,
                              hipStream_t stream)
{
  (void)in_sizes; (void)n_in; (void)out_size; (void)ws_size;
  const float* x    = (const float*)d_in[0];
  const float* wq   = (const float*)d_in[1];
  const float* wk   = (const float*)d_in[2];
  const float* wv   = (const float*)d_in[3];
  const float* wr   = (const float*)d_in[4];
  const float* wvr  = (const float*)d_in[5];
  const float* wj   = (const float*)d_in[6];
  const float* gate = (const float*)d_in[7];
  const float* wo   = (const float*)d_in[8];
  float* out = (float*)d_out;

  const int T = TT, E = EE, H = HH;
  const int nqt = T / 64;
  const size_t TE = (size_t)T * E;
  const size_t EE2 = (size_t)E * E;
  const size_t TT2 = (size_t)T * T;

  ushort* u = (ushort*)d_ws;
  ushort* xbf   = u;
  ushort* xh    = xbf + TE;
  ushort* wqb   = xh + TE;
  ushort* wkb   = wqb + EE2;
  ushort* wvb   = wkb + EE2;
  ushort* wvrb  = wvb + EE2;
  ushort* wob   = wvrb + EE2;
  ushort* wjh   = wob + EE2;
  ushort* qhb   = wjh + EE2;      // (H,T,64) bf16
  ushort* khb   = qhb + TE;       // (H,T,64) bf16
  ushort* vtb   = khb + TE;       // (H,64,T) bf16
  ushort* rvhb  = vtb + TE;       // (H,T,64) bf16
  ushort* echoT = rvhb + TE;      // (E,T)    bf16
  ushort* a1b   = echoT + TE;     // (H,T,64) bf16
  ushort* a2b   = a1b + TE;       // (H,T,64) bf16
  ushort* Wbf   = a2b + TE;       // (T,T)    bf16
  ushort* combb = Wbf + TT2;      // (T,E)    bf16
  float* jraw   = (float*)(combb + TE);   // (T,E) fp32
  float* wwb    = jraw + TE;              // (H,T)
  float* snorm  = wwb + (size_t)H * T;    // (T)
  float* denj   = snorm + T;              // (T)
  float* rpart  = denj + T;               // (16,H,T)
  float* segsum = rpart + (size_t)16 * H * T;   // (H,32,65)
  float* xT     = segsum + (size_t)H * 32 * 65; // (E,T) fp32
  float* pbuf   = xT + TE;                // (H,nqt,2,4160) fp32 ~17MB

  dim3 blk(256);
  cvt_x_k<<<(int)(TE / 1024), blk, 0, stream>>>(x, xbf, xh, snorm, (int)TE);
  cvt_w_k<<<dim3((int)(EE2 / 1024), 6), blk, 0, stream>>>(
      wq, wk, wv, wvr, wo, wj, wqb, wkb, wvb, wvrb, wob, wjh, (int)EE2);
  transpose_k<<<dim3(E / 32, T / 32), blk, 0, stream>>>(x, xT, T, E);

  // 4 bf16 projections + echo(f16) in one dispatch
  proj5<<<dim3(E / 128, T / 128, 5), blk, 0, stream>>>(
      xbf, xh, wqb, wkb, wvb, wvrb, wjh,
      qhb, khb, vtb, rvhb, echoT, snorm, T, E, E);

  // branch 2 scores
  rscore3<<<dim3(T / 1024, H, 16), blk, 0, stream>>>(xT, wr, rpart, T, E);
  rsoftmax2<<<H, blk, 0, stream>>>(rpart, wwb, T);

  // branch 1: flash split-K + merge
  flash_mfma<<<dim3(H, nqt, 2), blk, 0, stream>>>(qhb, khb, vtb, pbuf, T, nqt);
  flash_merge<<<H * nqt, blk, 0, stream>>>(pbuf, a1b, T, nqt);

  // branch 2: prefix scan
  rrp_part<<<dim3(H, 32), dim3(64), 0, stream>>>(wwb, rvhb, segsum, T);
  rrp_scan2<<<dim3(H, 32), dim3(64), 0, stream>>>(wwb, rvhb, segsum, a2b, T);

  // branch 3: W + causal GEMM
  janus_w<<<T, blk, 0, stream>>>(snorm, Wbf, denj, T);
  gemm_mfma<true><<<dim3(E / 128, T / 128), blk, 0, stream>>>(
      Wbf, echoT, jraw, T, E, T);

  // combine + output projection
  combine_kernel<<<(int)(TE / 256), blk, 0, stream>>>(a1b, a2b, jraw, denj,
                                                      gate, combb, T);
  gemm_mfma<false><<<dim3(E / 128, T / 128), blk, 0, stream>>>(
      combb, wob, (float*)out, T, E, E);
}

// Round 7
// 509.732 us; speedup vs baseline: 5.3906x; 1.0226x over previous
//
#include <hip/hip_runtime.h>
#include <cstddef>
#include <cstdint>

#define TT 2048
#define EE 1024
#define HH 16

typedef unsigned short ushort;
typedef unsigned int uint;
typedef __attribute__((ext_vector_type(8))) short short8;
typedef __attribute__((ext_vector_type(8))) _Float16 half8;
typedef __attribute__((ext_vector_type(4))) float f32x4;
typedef __attribute__((ext_vector_type(4))) ushort ushort4v;

__device__ __forceinline__ ushort f2bf(float f) {
  uint u = __builtin_bit_cast(uint, f);
  u = (u + 0x7FFFu + ((u >> 16) & 1u)) >> 16;
  return (ushort)u;
}
__device__ __forceinline__ float bf2f(ushort h) {
  return __builtin_bit_cast(float, (uint)h << 16);
}

// async global->LDS, 16B per lane; lds dest = wave-uniform base + lane*16
__device__ __forceinline__ void async16(ushort* lds, const ushort* g) {
  __builtin_amdgcn_global_load_lds(
      reinterpret_cast<const __attribute__((address_space(1))) void*>(
          reinterpret_cast<uintptr_t>(g)),
      reinterpret_cast<__attribute__((address_space(3))) void*>(
          static_cast<unsigned int>(reinterpret_cast<uintptr_t>(lds))),
      16, 0, 0);
}

// ---------------------------------------------------------------------------
// Conversions (fused). cvt_x also zeroes snorm (block 0).
// ---------------------------------------------------------------------------
__global__ __launch_bounds__(256) void cvt_x_k(
    const float* __restrict__ in, ushort* __restrict__ obf,
    ushort* __restrict__ oh, float* __restrict__ snorm, int n) {
  if (blockIdx.x == 0) {
    for (int i = threadIdx.x; i < TT; i += 256) snorm[i] = 0.f;
  }
  int i = (blockIdx.x * 256 + threadIdx.x) * 4;
  if (i >= n) return;
  float4 v = *(const float4*)(in + i);
  ushort4v b, h;
  b.x = f2bf(v.x); b.y = f2bf(v.y); b.z = f2bf(v.z); b.w = f2bf(v.w);
  h.x = __builtin_bit_cast(ushort, (_Float16)v.x);
  h.y = __builtin_bit_cast(ushort, (_Float16)v.y);
  h.z = __builtin_bit_cast(ushort, (_Float16)v.z);
  h.w = __builtin_bit_cast(ushort, (_Float16)v.w);
  *(ushort4v*)(obf + i) = b;
  *(ushort4v*)(oh + i) = h;
}

__global__ __launch_bounds__(256) void cvt_w_k(
    const float* __restrict__ s0, const float* __restrict__ s1,
    const float* __restrict__ s2, const float* __restrict__ s3,
    const float* __restrict__ s4, const float* __restrict__ s5,
    ushort* __restrict__ d0, ushort* __restrict__ d1,
    ushort* __restrict__ d2, ushort* __restrict__ d3,
    ushort* __restrict__ d4, ushort* __restrict__ d5, int n) {
  const int which = blockIdx.y;
  const float* src; ushort* dst;
  switch (which) {
    case 0: src = s0; dst = d0; break;
    case 1: src = s1; dst = d1; break;
    case 2: src = s2; dst = d2; break;
    case 3: src = s3; dst = d3; break;
    case 4: src = s4; dst = d4; break;
    default: src = s5; dst = d5; break;
  }
  int i = (blockIdx.x * 256 + threadIdx.x) * 4;
  if (i >= n) return;
  float4 v = *(const float4*)(src + i);
  ushort4v o;
  if (which == 5) {
    o.x = __builtin_bit_cast(ushort, (_Float16)v.x);
    o.y = __builtin_bit_cast(ushort, (_Float16)v.y);
    o.z = __builtin_bit_cast(ushort, (_Float16)v.z);
    o.w = __builtin_bit_cast(ushort, (_Float16)v.w);
  } else {
    o.x = f2bf(v.x); o.y = f2bf(v.y); o.z = f2bf(v.z); o.w = f2bf(v.w);
  }
  *(ushort4v*)(dst + i) = o;
}

// ---------------------------------------------------------------------------
// x (T,E) fp32 -> xT (E,T) fp32, 32x32 LDS tiles
// ---------------------------------------------------------------------------
__global__ __launch_bounds__(256) void transpose_k(
    const float* __restrict__ in, float* __restrict__ outT, int M, int N)
{
  __shared__ float tile[32][33];
  const int bn = blockIdx.x * 32;
  const int bm = blockIdx.y * 32;
  const int tx = threadIdx.x & 31, ty = threadIdx.x >> 5;
#pragma unroll
  for (int i = 0; i < 32; i += 8)
    tile[ty + i][tx] = in[(size_t)(bm + ty + i) * N + bn + tx];
  __syncthreads();
#pragma unroll
  for (int i = 0; i < 32; i += 8)
    outT[(size_t)(bn + ty + i) * M + bm + tx] = tile[tx][ty + i];
}

// ---------------------------------------------------------------------------
// Merged 5-way projection GEMM with global_load_lds staging (m97 pattern).
// z=0..3: bf16 x@W^T -> qhb/khb(OM1), vtb(OM2), rvhb(OM1)
// z=4:    f16  xh@wjh^T -> echoT (E,T bf16, OM3) + snorm row norms
// LDS tile: As/Bs[row][32] ushort (64B rows). Chunk j of wave w = rows
// (w*2+j)*16..+15; lane -> row chunk+lane/4, col (lane&3)*8.
// ---------------------------------------------------------------------------
__global__ __launch_bounds__(256) void proj5(
    const ushort* __restrict__ Abf, const ushort* __restrict__ Ah,
    const ushort* __restrict__ B0, const ushort* __restrict__ B1,
    const ushort* __restrict__ B2, const ushort* __restrict__ B3,
    const ushort* __restrict__ B4,
    ushort* __restrict__ C0, ushort* __restrict__ C1,
    ushort* __restrict__ C2, ushort* __restrict__ C3,
    ushort* __restrict__ C4, float* __restrict__ snorm,
    int M, int N, int K)
{
  const ushort* A; const ushort* B; ushort* C; int om;
  switch (blockIdx.z) {
    case 0: A = Abf; B = B0; C = C0; om = 1; break;
    case 1: A = Abf; B = B1; C = C1; om = 1; break;
    case 2: A = Abf; B = B2; C = C2; om = 2; break;
    case 3: A = Abf; B = B3; C = C3; om = 1; break;
    default: A = Ah; B = B4; C = C4; om = 3; break;
  }
  const bool f16 = (blockIdx.z == 4);
  __shared__ __align__(16) ushort As[128 * 32];
  __shared__ __align__(16) ushort Bs[128 * 32];
  const int tid = threadIdx.x;
  const int m0 = blockIdx.y * 128, n0 = blockIdx.x * 128;
  const int w = tid >> 6, lane = tid & 63;
  const int wr = w >> 1, wc = w & 1;
  const int lr = lane & 15, lk = lane >> 4;
  // staging addresses
  const int grow = w * 32 + (lane >> 2);        // row for chunk j=0 (j=1: +16)
  const int gcol = (lane & 3) * 8;
  const ushort* AgL = A + (size_t)(m0 + grow) * K + gcol;
  const ushort* BgL = B + (size_t)(n0 + grow) * K + gcol;
  ushort* AsW = As + w * 1024;                  // 2 chunks x 512 ushorts
  ushort* BsW = Bs + w * 1024;
  f32x4 acc[4][4] = {};
  for (int k0 = 0; k0 < K; k0 += 32) {
    __syncthreads();
    async16(AsW,       AgL + k0);
    async16(AsW + 512, AgL + k0 + (size_t)16 * K);
    async16(BsW,       BgL + k0);
    async16(BsW + 512, BgL + k0 + (size_t)16 * K);
    __syncthreads();
    short8 af[4], bf[4];
#pragma unroll
    for (int i = 0; i < 4; ++i)
      af[i] = *(const short8*)(As + (wr * 64 + i * 16 + lr) * 32 + lk * 8);
#pragma unroll
    for (int j = 0; j < 4; ++j)
      bf[j] = *(const short8*)(Bs + (wc * 64 + j * 16 + lr) * 32 + lk * 8);
    if (f16) {
#pragma unroll
      for (int i = 0; i < 4; ++i)
#pragma unroll
        for (int j = 0; j < 4; ++j)
          acc[i][j] = __builtin_amdgcn_mfma_f32_16x16x32_f16(
              __builtin_bit_cast(half8, af[i]), __builtin_bit_cast(half8, bf[j]),
              acc[i][j], 0, 0, 0);
    } else {
#pragma unroll
      for (int i = 0; i < 4; ++i)
#pragma unroll
        for (int j = 0; j < 4; ++j)
          acc[i][j] = __builtin_amdgcn_mfma_f32_16x16x32_bf16(
              af[i], bf[j], acc[i][j], 0, 0, 0);
    }
  }
#pragma unroll
  for (int i = 0; i < 4; ++i)
#pragma unroll
    for (int r = 0; r < 4; ++r) {
      int row = m0 + wr * 64 + i * 16 + lk * 4 + r;
#pragma unroll
      for (int j = 0; j < 4; ++j) {
        int col = n0 + wc * 64 + j * 16 + lr;
        ushort v = f2bf(acc[i][j][r]);
        if (om == 1)
          C[((size_t)(col >> 6) * M + row) * 64 + (col & 63)] = v;
        else if (om == 2)
          C[(size_t)(col >> 6) * 64 * M + (size_t)(col & 63) * M + row] = v;
        else
          C[(size_t)col * M + row] = v;
      }
    }
  if (om == 3) {
#pragma unroll
    for (int i = 0; i < 4; ++i)
#pragma unroll
      for (int r = 0; r < 4; ++r) {
        float p = 0.f;
#pragma unroll
        for (int j = 0; j < 4; ++j) p += acc[i][j][r] * acc[i][j][r];
        p += __shfl_xor(p, 1); p += __shfl_xor(p, 2);
        p += __shfl_xor(p, 4); p += __shfl_xor(p, 8);
        if (lr == 0)
          atomicAdd(&snorm[m0 + wr * 64 + i * 16 + lk * 4 + r], p);
      }
  }
}

// ---------------------------------------------------------------------------
// Generic MFMA GEMM (janus / out), fp32 out, global_load_lds staging.
// CZ: causal A (skip k0 >= m0+128).
// ---------------------------------------------------------------------------
template<bool CZ>
__global__ __launch_bounds__(256) void gemm_mfma(
    const ushort* __restrict__ A, const ushort* __restrict__ B,
    float* __restrict__ Cp, int M, int N, int K)
{
  __shared__ __align__(16) ushort As[128 * 32];
  __shared__ __align__(16) ushort Bs[128 * 32];
  const int tid = threadIdx.x;
  const int m0 = blockIdx.y * 128, n0 = blockIdx.x * 128;
  const int w = tid >> 6, lane = tid & 63;
  const int wr = w >> 1, wc = w & 1;
  const int lr = lane & 15, lk = lane >> 4;
  const int grow = w * 32 + (lane >> 2);
  const int gcol = (lane & 3) * 8;
  const ushort* AgL = A + (size_t)(m0 + grow) * K + gcol;
  const ushort* BgL = B + (size_t)(n0 + grow) * K + gcol;
  ushort* AsW = As + w * 1024;
  ushort* BsW = Bs + w * 1024;
  f32x4 acc[4][4] = {};
  const int Keff = CZ ? (K < m0 + 128 ? K : m0 + 128) : K;
  for (int k0 = 0; k0 < Keff; k0 += 32) {
    __syncthreads();
    async16(AsW,       AgL + k0);
    async16(AsW + 512, AgL + k0 + (size_t)16 * K);
    async16(BsW,       BgL + k0);
    async16(BsW + 512, BgL + k0 + (size_t)16 * K);
    __syncthreads();
    short8 af[4], bf[4];
#pragma unroll
    for (int i = 0; i < 4; ++i)
      af[i] = *(const short8*)(As + (wr * 64 + i * 16 + lr) * 32 + lk * 8);
#pragma unroll
    for (int j = 0; j < 4; ++j)
      bf[j] = *(const short8*)(Bs + (wc * 64 + j * 16 + lr) * 32 + lk * 8);
#pragma unroll
    for (int i = 0; i < 4; ++i)
#pragma unroll
      for (int j = 0; j < 4; ++j)
        acc[i][j] = __builtin_amdgcn_mfma_f32_16x16x32_bf16(
            af[i], bf[j], acc[i][j], 0, 0, 0);
  }
#pragma unroll
  for (int i = 0; i < 4; ++i)
#pragma unroll
    for (int r = 0; r < 4; ++r) {
      int row = m0 + wr * 64 + i * 16 + lk * 4 + r;
#pragma unroll
      for (int j = 0; j < 4; ++j) {
        int col = n0 + wc * 64 + j * 16 + lr;
        Cp[(size_t)row * N + col] = acc[i][j][r];
      }
    }
}

// ---------------------------------------------------------------------------
// Flash attention v4: split-K (round-6, unchanged).
// ---------------------------------------------------------------------------
__global__ __launch_bounds__(256) void flash_mfma(
    const ushort* __restrict__ Qg, const ushort* __restrict__ Kg,
    const ushort* __restrict__ Vg, float* __restrict__ pbuf, int T, int nqt)
{
  const int h = blockIdx.x;
  const int qt = nqt - 1 - blockIdx.y;
  const int sp = blockIdx.z;
  const int q0 = qt * 64;
  const int nk = qt + 1;
  const int span = (nk + 1) >> 1;
  const int kb = sp * span;
  const int ke = (nk < kb + span) ? nk : (kb + span);
  const int tid = threadIdx.x, w = tid >> 6, lane = tid & 63;
  const int lr = lane & 15, lk = lane >> 4;
  const ushort* Q = Qg + (size_t)h * T * 64;
  const ushort* K = Kg + (size_t)h * T * 64;
  const ushort* V = Vg + (size_t)h * 64 * T;
  __shared__ __align__(16) ushort Ps[4][16 * 72];
  const float CEXP = 0.18033688f;  // 0.125 * log2(e)

  f32x4 o[4] = {};
  float ls[4] = {0.f, 0.f, 0.f, 0.f};

  if (kb < ke) {
    short8 qa0 = *(const short8*)(Q + (size_t)(q0 + w * 16 + lr) * 64 + lk * 8);
    short8 qa1 = *(const short8*)(Q + (size_t)(q0 + w * 16 + lr) * 64 + 32 + lk * 8);
    short8 kb0[4], kb1[4];
#pragma unroll
    for (int c = 0; c < 4; ++c) {
      const ushort* kp = K + (size_t)(kb * 64 + c * 16 + lr) * 64 + lk * 8;
      kb0[c] = *(const short8*)kp;
      kb1[c] = *(const short8*)(kp + 32);
    }
    for (int kt = kb; kt < ke; ++kt) {
      const int k0 = kt * 64;
      short8 vb0[4], vb1[4];
#pragma unroll
      for (int c = 0; c < 4; ++c) {
        const ushort* vp = V + (size_t)(c * 16 + lr) * T + k0 + lk * 8;
        vb0[c] = *(const short8*)vp;
        vb1[c] = *(const short8*)(vp + 32);
      }
      f32x4 s[4];
#pragma unroll
      for (int c = 0; c < 4; ++c) {
        f32x4 z = {};
        z = __builtin_amdgcn_mfma_f32_16x16x32_bf16(qa0, kb0[c], z, 0, 0, 0);
        z = __builtin_amdgcn_mfma_f32_16x16x32_bf16(qa1, kb1[c], z, 0, 0, 0);
        s[c] = z;
      }
      if (kt + 1 < ke) {
#pragma unroll
        for (int c = 0; c < 4; ++c) {
          const ushort* kp = K + (size_t)(k0 + 64 + c * 16 + lr) * 64 + lk * 8;
          kb0[c] = *(const short8*)kp;
          kb1[c] = *(const short8*)(kp + 32);
        }
      }
      const bool diag = (kt == qt);
      const int rowbase = q0 + w * 16 + lk * 4;
#pragma unroll
      for (int c = 0; c < 4; ++c) {
        const int col = k0 + c * 16 + lr;
#pragma unroll
        for (int r = 0; r < 4; ++r) {
          float p = exp2f(s[c][r] * CEXP);
          if (diag && col > rowbase + r) p = 0.f;
          ls[r] += p;
          Ps[w][(lk * 4 + r) * 72 + c * 16 + lr] = f2bf(p);
        }
      }
      short8 pa0 = *(const short8*)(&Ps[w][lr * 72 + lk * 8]);
      short8 pa1 = *(const short8*)(&Ps[w][lr * 72 + 32 + lk * 8]);
#pragma unroll
      for (int c = 0; c < 4; ++c) {
        o[c] = __builtin_amdgcn_mfma_f32_16x16x32_bf16(pa0, vb0[c], o[c], 0, 0, 0);
        o[c] = __builtin_amdgcn_mfma_f32_16x16x32_bf16(pa1, vb1[c], o[c], 0, 0, 0);
      }
    }
#pragma unroll
    for (int r = 0; r < 4; ++r) {
      ls[r] += __shfl_xor(ls[r], 1);
      ls[r] += __shfl_xor(ls[r], 2);
      ls[r] += __shfl_xor(ls[r], 4);
      ls[r] += __shfl_xor(ls[r], 8);
    }
  }
  float* pb = pbuf + ((size_t)(h * nqt + qt) * 2 + sp) * 4160;
#pragma unroll
  for (int c = 0; c < 4; ++c)
#pragma unroll
    for (int r = 0; r < 4; ++r) {
      int row = w * 16 + lk * 4 + r;
      pb[(size_t)row * 64 + c * 16 + lr] = o[c][r];
    }
  if (lr == 0) {
#pragma unroll
    for (int r = 0; r < 4; ++r)
      pb[4096 + w * 16 + lk * 4 + r] = ls[r];
  }
}

__global__ __launch_bounds__(256) void flash_merge(
    const float* __restrict__ pbuf, ushort* __restrict__ O, int T, int nqt)
{
  const int b = blockIdx.x;
  const int h = b / nqt, qt = b - h * nqt;
  const float* p0 = pbuf + (size_t)b * 2 * 4160;
  const float* p1 = p0 + 4160;
  ushort* Oh = O + ((size_t)h * T + qt * 64) * 64;
  __shared__ float lsum[64];
  if (threadIdx.x < 64)
    lsum[threadIdx.x] = p0[4096 + threadIdx.x] + p1[4096 + threadIdx.x];
  __syncthreads();
  for (int i = threadIdx.x; i < 4096; i += 256) {
    int r = i >> 6;
    Oh[i] = f2bf((p0[i] + p1[i]) / lsum[r]);
  }
}

// ---------------------------------------------------------------------------
// Branch 2: r-score (both streams coalesced via xT)
// ---------------------------------------------------------------------------
__global__ __launch_bounds__(256) void rscore3(
    const float* __restrict__ xT, const float* __restrict__ wr,
    float* __restrict__ rpart, int T, int E)
{
  const int h = blockIdx.y;
  const int e0 = blockIdx.z * 64;
  const int t0 = (blockIdx.x * 256 + threadIdx.x) * 4;
  const float* wrh = wr + (size_t)h * E * T;
  float4 acc = {0.f, 0.f, 0.f, 0.f};
#pragma unroll 4
  for (int e = e0; e < e0 + 64; ++e) {
    float4 xv = *(const float4*)(xT + (size_t)e * T + t0);
    float4 wv = *(const float4*)(wrh + (size_t)e * T + t0);
    acc.x += xv.x * wv.x;
    acc.y += xv.y * wv.y;
    acc.z += xv.z * wv.z;
    acc.w += xv.w * wv.w;
  }
  *(float4*)(rpart + ((size_t)blockIdx.z * HH + h) * T + t0) = acc;
}

__global__ __launch_bounds__(256) void rsoftmax2(
    const float* __restrict__ rpart, float* __restrict__ w, int T)
{
  const int h = blockIdx.x;
  __shared__ float rs[TT];
  __shared__ float red[4];
  for (int t = threadIdx.x; t < T; t += 256) {
    float a = 0.f;
#pragma unroll
    for (int s = 0; s < 16; ++s) a += rpart[((size_t)s * HH + h) * T + t];
    rs[t] = a;
  }
  __syncthreads();
  float mx = -1e30f;
  for (int t = threadIdx.x; t < T; t += 256) mx = fmaxf(mx, rs[t]);
#pragma unroll
  for (int o = 32; o; o >>= 1) mx = fmaxf(mx, __shfl_xor(mx, o));
  if ((threadIdx.x & 63) == 0) red[threadIdx.x >> 6] = mx;
  __syncthreads();
  mx = fmaxf(fmaxf(red[0], red[1]), fmaxf(red[2], red[3]));
  float* wh = w + (size_t)h * T;
  for (int t = threadIdx.x; t < T; t += 256)
    wh[t] = __expf((rs[t] - mx) * 0.125f);
}

// ---------------------------------------------------------------------------
// RRP prefix scan, two passes, grid (H,32) x 1 wave.
// ---------------------------------------------------------------------------
__global__ __launch_bounds__(64) void rrp_part(
    const float* __restrict__ wgt, const ushort* __restrict__ rv,
    float* __restrict__ segsum, int T)
{
  const int h = blockIdx.x, seg = blockIdx.y, d = threadIdx.x;
  const int segLen = T >> 5;
  const float* wh = wgt + (size_t)h * T;
  const ushort* rvh = rv + (size_t)h * T * 64;
  const int kbeg = seg * segLen, kend = kbeg + segLen;
  float num = 0.f, den = 0.f;
  for (int k = kbeg; k < kend; ++k) {
    float wk = wh[k];
    num += wk * bf2f(rvh[(size_t)k * 64 + d]);
    den += wk;
  }
  float* o = segsum + ((size_t)h * 32 + seg) * 65;
  o[d] = num;
  if (d == 0) o[64] = den;
}

__global__ __launch_bounds__(64) void rrp_scan2(
    const float* __restrict__ wgt, const ushort* __restrict__ rv,
    const float* __restrict__ segsum, ushort* __restrict__ out, int T)
{
  const int h = blockIdx.x, seg = blockIdx.y, d = threadIdx.x;
  const int segLen = T >> 5;
  const float* wh = wgt + (size_t)h * T;
  const ushort* rvh = rv + (size_t)h * T * 64;
  ushort* oh = out + (size_t)h * T * 64;
  float num = 0.f, den = 0.f;
  for (int s = 0; s < seg; ++s) {
    const float* p = segsum + ((size_t)h * 32 + s) * 65;
    num += p[d];
    den += p[64];
  }
  const int kbeg = seg * segLen, kend = kbeg + segLen;
  for (int k = kbeg; k < kend; ++k) {
    float wk = wh[k];
    num += wk * bf2f(rvh[(size_t)k * 64 + d]);
    den += wk;
    oh[(size_t)k * 64 + d] = f2bf(num / den);
  }
}

// ---------------------------------------------------------------------------
// Branch 3: W[q][k] (bf16) + row denominators.
// ---------------------------------------------------------------------------
__global__ __launch_bounds__(256) void janus_w(
    const float* __restrict__ snorm, ushort* __restrict__ Wb,
    float* __restrict__ den, int T)
{
  const int q = blockIdx.x;
  const float sq = snorm[q] * 0.03125f;
  float mx = -1e30f;
  for (int k = threadIdx.x; k <= q; k += 256)
    mx = fmaxf(mx, sq * (snorm[k] * 0.03125f));
#pragma unroll
  for (int o = 32; o; o >>= 1) mx = fmaxf(mx, __shfl_xor(mx, o));
  __shared__ float red[4];
  if ((threadIdx.x & 63) == 0) red[threadIdx.x >> 6] = mx;
  __syncthreads();
  mx = fmaxf(fmaxf(red[0], red[1]), fmaxf(red[2], red[3]));
  float sum = 0.f;
  ushort* Wq = Wb + (size_t)q * T;
  for (int k = threadIdx.x; k < T; k += 256) {
    float wv = (k <= q) ? __expf(sq * (snorm[k] * 0.03125f) - mx) : 0.f;
    ushort wb = f2bf(wv);
    Wq[k] = wb;
    sum += bf2f(wb);
  }
#pragma unroll
  for (int o = 32; o; o >>= 1) sum += __shfl_xor(sum, o);
  __syncthreads();
  if ((threadIdx.x & 63) == 0) red[threadIdx.x >> 6] = sum;
  __syncthreads();
  if (threadIdx.x == 0) den[q] = red[0] + red[1] + red[2] + red[3];
}

// ---------------------------------------------------------------------------
// Gated combine -> comb bf16 (T,E)
// ---------------------------------------------------------------------------
__global__ __launch_bounds__(256) void combine_kernel(
    const ushort* __restrict__ a1, const ushort* __restrict__ a2,
    const float* __restrict__ jraw, const float* __restrict__ denj,
    const float* __restrict__ gate, ushort* __restrict__ comb, int T)
{
  const int idx = blockIdx.x * 256 + threadIdx.x;
  const int t = idx >> 10;
  const int c = idx & 1023;
  const int h = c >> 6;
  const int d = c & 63;
  float g0 = gate[h * 3 + 0], g1 = gate[h * 3 + 1], g2 = gate[h * 3 + 2];
  float mg = fmaxf(g0, fmaxf(g1, g2));
  float e0 = __expf(g0 - mg), e1 = __expf(g1 - mg), e2 = __expf(g2 - mg);
  float inv = 1.f / (e0 + e1 + e2);
  const size_t hd = ((size_t)h * T + t) * 64 + d;
  float v = (e0 * bf2f(a1[hd]) + e1 * bf2f(a2[hd]) + e2 * jraw[idx] / denj[t]) * inv;
  comb[idx] = f2bf(v);
}

// ---------------------------------------------------------------------------
extern "C" void kernel_launch(void* const* d_in, const int* in_sizes, int n_in,
                              void* d_out, int out_size, void* d_ws, size_t ws_size,
                              hipStream_t stream)
{
  (void)in_sizes; (void)n_in; (void)out_size; (void)ws_size;
  const float* x    = (const float*)d_in[0];
  const float* wq   = (const float*)d_in[1];
  const float* wk   = (const float*)d_in[2];
  const float* wv   = (const float*)d_in[3];
  const float* wr   = (const float*)d_in[4];
  const float* wvr  = (const float*)d_in[5];
  const float* wj   = (const float*)d_in[6];
  const float* gate = (const float*)d_in[7];
  const float* wo   = (const float*)d_in[8];
  float* out = (float*)d_out;

  const int T = TT, E = EE, H = HH;
  const int nqt = T / 64;
  const size_t TE = (size_t)T * E;
  const size_t EE2 = (size_t)E * E;
  const size_t TT2 = (size_t)T * T;

  ushort* u = (ushort*)d_ws;
  ushort* xbf   = u;
  ushort* xh    = xbf + TE;
  ushort* wqb   = xh + TE;
  ushort* wkb   = wqb + EE2;
  ushort* wvb   = wkb + EE2;
  ushort* wvrb  = wvb + EE2;
  ushort* wob   = wvrb + EE2;
  ushort* wjh   = wob + EE2;
  ushort* qhb   = wjh + EE2;      // (H,T,64) bf16
  ushort* khb   = qhb + TE;       // (H,T,64) bf16
  ushort* vtb   = khb + TE;       // (H,64,T) bf16
  ushort* rvhb  = vtb + TE;       // (H,T,64) bf16
  ushort* echoT = rvhb + TE;      // (E,T)    bf16
  ushort* a1b   = echoT + TE;     // (H,T,64) bf16
  ushort* a2b   = a1b + TE;       // (H,T,64) bf16
  ushort* Wbf   = a2b + TE;       // (T,T)    bf16
  ushort* combb = Wbf + TT2;      // (T,E)    bf16
  float* jraw   = (float*)(combb + TE);   // (T,E) fp32
  float* wwb    = jraw + TE;              // (H,T)
  float* snorm  = wwb + (size_t)H * T;    // (T)
  float* denj   = snorm + T;              // (T)
  float* rpart  = denj + T;               // (16,H,T)
  float* segsum = rpart + (size_t)16 * H * T;   // (H,32,65)
  float* xT     = segsum + (size_t)H * 32 * 65; // (E,T) fp32
  float* pbuf   = xT + TE;                // (H,nqt,2,4160) fp32

  dim3 blk(256);
  cvt_x_k<<<(int)(TE / 1024), blk, 0, stream>>>(x, xbf, xh, snorm, (int)TE);
  cvt_w_k<<<dim3((int)(EE2 / 1024), 6), blk, 0, stream>>>(
      wq, wk, wv, wvr, wo, wj, wqb, wkb, wvb, wvrb, wob, wjh, (int)EE2);
  transpose_k<<<dim3(E / 32, T / 32), blk, 0, stream>>>(x, xT, T, E);

  // 4 bf16 projections + echo(f16) in one dispatch (async LDS staging)
  proj5<<<dim3(E / 128, T / 128, 5), blk, 0, stream>>>(
      xbf, xh, wqb, wkb, wvb, wvrb, wjh,
      qhb, khb, vtb, rvhb, echoT, snorm, T, E, E);

  // branch 2 scores
  rscore3<<<dim3(T / 1024, H, 16), blk, 0, stream>>>(xT, wr, rpart, T, E);
  rsoftmax2<<<H, blk, 0, stream>>>(rpart, wwb, T);

  // branch 1: flash split-K + merge
  flash_mfma<<<dim3(H, nqt, 2), blk, 0, stream>>>(qhb, khb, vtb, pbuf, T, nqt);
  flash_merge<<<H * nqt, blk, 0, stream>>>(pbuf, a1b, T, nqt);

  // branch 2: prefix scan
  rrp_part<<<dim3(H, 32), dim3(64), 0, stream>>>(wwb, rvhb, segsum, T);
  rrp_scan2<<<dim3(H, 32), dim3(64), 0, stream>>>(wwb, rvhb, segsum, a2b, T);

  // branch 3: W + causal GEMM
  janus_w<<<T, blk, 0, stream>>>(snorm, Wbf, denj, T);
  gemm_mfma<true><<<dim3(E / 128, T / 128), blk, 0, stream>>>(
      Wbf, echoT, jraw, T, E, T);

  // combine + output projection
  combine_kernel<<<(int)(TE / 256), blk, 0, stream>>>(a1b, a2b, jraw, denj,
                                                      gate, combb, T);
  gemm_mfma<false><<<dim3(E / 128, T / 128), blk, 0, stream>>>(
      combb, wob, (float*)out, T, E, E);
}